// Round 1
// baseline (5117.827 us; speedup 1.0000x reference)
//
#include <hip/hip_runtime.h>
#include <hip/hip_bf16.h>
#include <math.h>

#define B 64
#define K 3
#define H 4096
#define V 32000
#define K1 (K + 1)

// ---------------- workspace layout (bytes) ----------------
// target   : 256 int
// tok_ws   : 64 int
// h_buf    : B*H float (1 MB)
// x_row    : B*H float (1 MB)
// x_T4     : B*H float as float4[(H/4)*B] (1 MB)
// u_T      : 2H*B float (2 MB)
// cand_val : 2000*64 float (512 KB)
// cand_idx : 2000*64 int   (512 KB)
// part     : 16*B*H float  (16 MB)
#define OFF_TARGET 0
#define OFF_TOK    4096
#define OFF_HBUF   8192
#define OFF_XROW   (OFF_HBUF + (1u << 20))
#define OFF_XT4    (OFF_XROW + (1u << 20))
#define OFF_UT     (OFF_XT4 + (1u << 20))
#define OFF_CVAL   (OFF_UT + (2u << 20))
#define OFF_CIDX   (OFF_CVAL + (512u << 10))
#define OFF_PART   (OFF_CIDX + (512u << 10))

// out layout: accepted[256] | num_accepted[64] | next_draft[192] | next_new[256] | new_past_t[192]
#define OUT_ACC 0
#define OUT_NA  256
#define OUT_NDT 320
#define OUT_NNT 512
#define OUT_NPT 768

// ------------------------------------------------------------------
// Kernel A: row-wise argmax of logits (256 rows x 32000), first-index tie-break
__global__ void argmax_logits_kernel(const float* __restrict__ logits, int* __restrict__ target) {
    const int r = blockIdx.x;
    const float4* row = (const float4*)(logits + (size_t)r * V);
    float bv = -INFINITY;
    int bi = 0x7fffffff;
    for (int i4 = threadIdx.x; i4 < V / 4; i4 += 256) {
        float4 v = row[i4];
        int base = i4 * 4;
        if (v.x > bv) { bv = v.x; bi = base; }
        if (v.y > bv) { bv = v.y; bi = base + 1; }
        if (v.z > bv) { bv = v.z; bi = base + 2; }
        if (v.w > bv) { bv = v.w; bi = base + 3; }
    }
    __shared__ float sv[256];
    __shared__ int si[256];
    sv[threadIdx.x] = bv; si[threadIdx.x] = bi;
    __syncthreads();
    for (int s = 128; s > 0; s >>= 1) {
        if (threadIdx.x < (unsigned)s) {
            float ov = sv[threadIdx.x + s]; int oi = si[threadIdx.x + s];
            if (ov > sv[threadIdx.x] || (ov == sv[threadIdx.x] && oi < si[threadIdx.x])) {
                sv[threadIdx.x] = ov; si[threadIdx.x] = oi;
            }
        }
        __syncthreads();
    }
    if (threadIdx.x == 0) target[r] = si[0];
}

// ------------------------------------------------------------------
// Kernel B: acceptance logic + outputs + h gather
__global__ void accept_kernel(const int* __restrict__ target, const int* __restrict__ draft,
                              const int* __restrict__ past_t, const int* __restrict__ slot,
                              const float* __restrict__ hs, int* __restrict__ out,
                              int* __restrict__ tok_ws, float* __restrict__ h_buf) {
    const int b = blockIdx.x;
    __shared__ int s_na;
    if (threadIdx.x == 0) {
        const int* trow = target + b * K1;
        const int* drow = draft + b * K;
        int na = 1, prod = 1;
        for (int k = 0; k < K; ++k) { prod *= (drow[k] == trow[k]) ? 1 : 0; na += prod; }
        s_na = na;
        out[OUT_NA + b] = na;
        int srow = slot[b];
        for (int jj = 0; jj < K; ++jj) {
            int idx = na + jj;
            int v = (idx < K) ? past_t[srow * K + idx] : trow[idx - K];
            out[OUT_NPT + b * K + jj] = v;
        }
        int tok0 = trow[na - 1];
        out[OUT_NNT + b * K1 + 0] = tok0;
        tok_ws[b] = tok0;
        for (int i = 0; i < K1; ++i) out[OUT_ACC + b * K1 + i] = trow[i];
    }
    __syncthreads();
    const int na = s_na;
    const float4* src = (const float4*)(hs + ((size_t)b * K1 + (na - 1)) * H);
    float4* dst = (float4*)(h_buf + (size_t)b * H);
    for (int k = threadIdx.x; k < H / 4; k += 256) dst[k] = src[k];
}

// ------------------------------------------------------------------
// Kernel C: gather embed row, rmsnorm both halves, write transposed u_T (p-major, b-minor)
__global__ void prep_u_kernel(const int* __restrict__ tok_ws, const float* __restrict__ embed,
                              const float* __restrict__ h_src, float* __restrict__ u_T) {
    const int b = blockIdx.x, tid = threadIdx.x;
    const int tok = tok_ws[b];
    const float4* e4 = (const float4*)(embed + (size_t)tok * H);
    const float4* h4 = (const float4*)(h_src + (size_t)b * H);
    float4 ev[4], hv[4];
    float sse = 0.f, ssh = 0.f;
#pragma unroll
    for (int k = 0; k < 4; ++k) {
        int i = tid + k * 256;
        float4 e = e4[i], h = h4[i];
        ev[k] = e; hv[k] = h;
        sse += e.x * e.x + e.y * e.y + e.z * e.z + e.w * e.w;
        ssh += h.x * h.x + h.y * h.y + h.z * h.z + h.w * h.w;
    }
    __shared__ float r1[256], r2[256];
    r1[tid] = sse; r2[tid] = ssh;
    __syncthreads();
    for (int s = 128; s > 0; s >>= 1) {
        if (tid < (unsigned)s) { r1[tid] += r1[tid + s]; r2[tid] += r2[tid + s]; }
        __syncthreads();
    }
    const float sE = 1.0f / sqrtf(r1[0] * (1.0f / H) + 1e-6f);
    const float sH = 1.0f / sqrtf(r2[0] * (1.0f / H) + 1e-6f);
#pragma unroll
    for (int k = 0; k < 4; ++k) {
        int i = tid + k * 256;
        int p = i * 4;
        u_T[(size_t)(p + 0) * B + b] = ev[k].x * sE;
        u_T[(size_t)(p + 1) * B + b] = ev[k].y * sE;
        u_T[(size_t)(p + 2) * B + b] = ev[k].z * sE;
        u_T[(size_t)(p + 3) * B + b] = ev[k].w * sE;
        u_T[(size_t)(H + p + 0) * B + b] = hv[k].x * sH;
        u_T[(size_t)(H + p + 1) * B + b] = hv[k].y * sH;
        u_T[(size_t)(H + p + 2) * B + b] = hv[k].z * sH;
        u_T[(size_t)(H + p + 3) * B + b] = hv[k].w * sH;
    }
}

// ------------------------------------------------------------------
// Kernel D: GEMM1 partial: x_part[c][b][o] = sum_{p in chunk c} u_T[p][b] * W[p][o]
// grid (16 o-blocks, 16 p-chunks), 256 threads; thread owns one o, acc over all 64 b.
__global__ __launch_bounds__(256) void gemm1_kernel(const float* __restrict__ u_T,
                                                    const float* __restrict__ W,
                                                    float* __restrict__ part) {
    const int o = blockIdx.x * 256 + threadIdx.x;
    const int p0 = blockIdx.y * 512;
    float acc[B];
#pragma unroll
    for (int i = 0; i < B; ++i) acc[i] = 0.f;
    for (int p = p0; p < p0 + 512; ++p) {
        const float wv = W[(size_t)p * H + o];
        const float* ur = u_T + (size_t)p * B;
#pragma unroll
        for (int b2 = 0; b2 < B; ++b2) acc[b2] = fmaf(ur[b2], wv, acc[b2]);
    }
    float* dst = part + ((size_t)blockIdx.y * B) * H + o;
#pragma unroll
    for (int b2 = 0; b2 < B; ++b2) dst[(size_t)b2 * H] = acc[b2];
}

// ------------------------------------------------------------------
// Kernel E: reduce 16 partial chunks -> x_row (b-major) and x_T4 (h4-major float4)
__global__ void gemm1_reduce_kernel(const float* __restrict__ part, float* __restrict__ x_row,
                                    float4* __restrict__ x_T4) {
    const int flat = blockIdx.x * 256 + threadIdx.x;  // 0..65535
    const int b = flat >> 10;
    const int o4 = flat & 1023;
    float4 s = make_float4(0.f, 0.f, 0.f, 0.f);
#pragma unroll
    for (int c = 0; c < 16; ++c) {
        const float4 v = *(const float4*)(part + ((size_t)(c * B + b)) * H + o4 * 4);
        s.x += v.x; s.y += v.y; s.z += v.z; s.w += v.w;
    }
    *(float4*)(x_row + (size_t)b * H + o4 * 4) = s;
    x_T4[(size_t)o4 * B + b] = s;
}

// ------------------------------------------------------------------
// Kernel F: GEMM2 + per-wave argmax candidates.
// dlog[b][v] = dot(x[b], lm_head[v]).  b = lane, 16 v per wave, 4 waves/block, 500 blocks.
__global__ __launch_bounds__(256) void gemm2_kernel(const float4* __restrict__ xT4,
                                                    const float* __restrict__ L,
                                                    float* __restrict__ cand_val,
                                                    int* __restrict__ cand_idx) {
    const int lane = threadIdx.x & 63;
    const int wave = __builtin_amdgcn_readfirstlane(threadIdx.x >> 6);
    const int vbase = blockIdx.x * 64 + wave * 16;
    const float4* L4 = (const float4*)L;
    float acc[16];
#pragma unroll
    for (int i = 0; i < 16; ++i) acc[i] = 0.f;
    for (int h4 = 0; h4 < H / 4; ++h4) {
        const float4 xv = xT4[(size_t)h4 * B + lane];
#pragma unroll
        for (int vi = 0; vi < 16; ++vi) {
            const float4 w = L4[(size_t)(vbase + vi) * (H / 4) + h4];
            float a = acc[vi];
            a = fmaf(w.x, xv.x, a);
            a = fmaf(w.y, xv.y, a);
            a = fmaf(w.z, xv.z, a);
            a = fmaf(w.w, xv.w, a);
            acc[vi] = a;
        }
    }
    // per-lane argmax over the 16 v's (ascending v -> strict > keeps first)
    float bv = acc[0];
    int bi = vbase;
#pragma unroll
    for (int vi = 1; vi < 16; ++vi) {
        if (acc[vi] > bv) { bv = acc[vi]; bi = vbase + vi; }
    }
    const int w = blockIdx.x * 4 + wave;
    cand_val[(size_t)w * B + lane] = bv;
    cand_idx[(size_t)w * B + lane] = bi;
}

// ------------------------------------------------------------------
// Kernel G: final argmax over 2000 wave candidates per b; writes tok + outputs for step j
__global__ void final_argmax_kernel(const float* __restrict__ cand_val, const int* __restrict__ cand_idx,
                                    int* __restrict__ tok_ws, int* __restrict__ out, int j) {
    const int b = blockIdx.x, tid = threadIdx.x;
    float bv = -INFINITY;
    int bi = 0x7fffffff;
    for (int w = tid; w < 2000; w += 256) {
        float v = cand_val[(size_t)w * B + b];
        int i = cand_idx[(size_t)w * B + b];
        if (v > bv || (v == bv && i < bi)) { bv = v; bi = i; }
    }
    __shared__ float sv[256];
    __shared__ int si[256];
    sv[tid] = bv; si[tid] = bi;
    __syncthreads();
    for (int s = 128; s > 0; s >>= 1) {
        if (tid < (unsigned)s) {
            float ov = sv[tid + s]; int oi = si[tid + s];
            if (ov > sv[tid] || (ov == sv[tid] && oi < si[tid])) { sv[tid] = ov; si[tid] = oi; }
        }
        __syncthreads();
    }
    if (tid == 0) {
        const int t = si[0];
        tok_ws[b] = t;
        out[OUT_NDT + b * K + j] = t;
        out[OUT_NNT + b * K1 + 1 + j] = t;
    }
}

// ------------------------------------------------------------------
extern "C" void kernel_launch(void* const* d_in, const int* in_sizes, int n_in,
                              void* d_out, int out_size, void* d_ws, size_t ws_size,
                              hipStream_t stream) {
    const float* logits  = (const float*)d_in[0];
    const float* hs      = (const float*)d_in[1];
    // d_in[2] past_hidden_pool: provably unused (num_accepted >= 1 => h always from hidden_states)
    const float* embed   = (const float*)d_in[3];
    const float* lm_head = (const float*)d_in[4];
    const float* mtp_fc  = (const float*)d_in[5];
    const int* draft     = (const int*)d_in[6];
    const int* past_t    = (const int*)d_in[7];
    const int* slot      = (const int*)d_in[8];
    int* out = (int*)d_out;

    char* ws = (char*)d_ws;
    int* target     = (int*)(ws + OFF_TARGET);
    int* tok_ws     = (int*)(ws + OFF_TOK);
    float* h_buf    = (float*)(ws + OFF_HBUF);
    float* x_row    = (float*)(ws + OFF_XROW);
    float4* x_T4    = (float4*)(ws + OFF_XT4);
    float* u_T      = (float*)(ws + OFF_UT);
    float* cand_val = (float*)(ws + OFF_CVAL);
    int* cand_idx   = (int*)(ws + OFF_CIDX);
    float* part     = (float*)(ws + OFF_PART);

    argmax_logits_kernel<<<B * K1, 256, 0, stream>>>(logits, target);
    accept_kernel<<<B, 256, 0, stream>>>(target, draft, past_t, slot, hs, out, tok_ws, h_buf);

    for (int j = 0; j < K; ++j) {
        const float* h_src = (j == 0) ? h_buf : x_row;
        prep_u_kernel<<<B, 256, 0, stream>>>(tok_ws, embed, h_src, u_T);
        gemm1_kernel<<<dim3(16, 16), 256, 0, stream>>>(u_T, mtp_fc + (size_t)j * 2 * H * H, part);
        gemm1_reduce_kernel<<<256, 256, 0, stream>>>(part, x_row, x_T4);
        gemm2_kernel<<<V / 64, 256, 0, stream>>>(x_T4, lm_head, cand_val, cand_idx);
        final_argmax_kernel<<<B, 256, 0, stream>>>(cand_val, cand_idx, tok_ws, out, j);
    }
}

// Round 2
// 2145.890 us; speedup vs baseline: 2.3849x; 2.3849x over previous
//
#include <hip/hip_runtime.h>
#include <hip/hip_bf16.h>
#include <math.h>

#define B 64
#define K 3
#define H 4096
#define V 32000
#define K1 (K + 1)

// ---------------- workspace layout (bytes) ----------------
#define OFF_TARGET 0                       // 256 int
#define OFF_TOK    4096                    // 64 int
#define OFF_SCALE  8192                    // 128 float (sE[64], sH[64])
#define OFF_HBUF   16384                   // B*H float (1 MB)
#define OFF_XROW   (OFF_HBUF + (1u<<20))   // B*H float (1 MB), x row-major [b][h]
#define OFF_XS     (OFF_XROW + (1u<<20))   // H*B float (1 MB), x transposed [h][b]
#define OFF_UT     (OFF_XS + (1u<<20))     // 2H*B float (2 MB), u transposed [p][b]
#define OFF_CVAL   (OFF_UT + (2u<<20))     // 50*64 float
#define OFF_CIDX   (OFF_CVAL + 16384)      // 50*64 int
#define OFF_PART   (OFF_CIDX + 16384)      // max(32*H*B, 4*V*B) float = 33.6 MB

// out layout: accepted[256] | num_accepted[64] | next_draft[192] | next_new[256] | new_past_t[192]
#define OUT_ACC 0
#define OUT_NA  256
#define OUT_NDT 320
#define OUT_NNT 512
#define OUT_NPT 768

// ------------------------------------------------------------------
// Kernel A: row-wise argmax of logits (256 rows x 32000), first-index tie-break
__global__ void argmax_logits_kernel(const float* __restrict__ logits, int* __restrict__ target) {
    const int r = blockIdx.x;
    const float4* row = (const float4*)(logits + (size_t)r * V);
    float bv = -INFINITY;
    int bi = 0x7fffffff;
    for (int i4 = threadIdx.x; i4 < V / 4; i4 += 256) {
        float4 v = row[i4];
        int base = i4 * 4;
        if (v.x > bv) { bv = v.x; bi = base; }
        if (v.y > bv) { bv = v.y; bi = base + 1; }
        if (v.z > bv) { bv = v.z; bi = base + 2; }
        if (v.w > bv) { bv = v.w; bi = base + 3; }
    }
    __shared__ float sv[256];
    __shared__ int si[256];
    sv[threadIdx.x] = bv; si[threadIdx.x] = bi;
    __syncthreads();
    for (int s = 128; s > 0; s >>= 1) {
        if (threadIdx.x < (unsigned)s) {
            float ov = sv[threadIdx.x + s]; int oi = si[threadIdx.x + s];
            if (ov > sv[threadIdx.x] || (ov == sv[threadIdx.x] && oi < si[threadIdx.x])) {
                sv[threadIdx.x] = ov; si[threadIdx.x] = oi;
            }
        }
        __syncthreads();
    }
    if (threadIdx.x == 0) target[r] = si[0];
}

// ------------------------------------------------------------------
// Kernel B: acceptance logic + outputs + h gather
__global__ void accept_kernel(const int* __restrict__ target, const int* __restrict__ draft,
                              const int* __restrict__ past_t, const int* __restrict__ slot,
                              const float* __restrict__ hs, int* __restrict__ out,
                              int* __restrict__ tok_ws, float* __restrict__ h_buf) {
    const int b = blockIdx.x;
    __shared__ int s_na;
    if (threadIdx.x == 0) {
        const int* trow = target + b * K1;
        const int* drow = draft + b * K;
        int na = 1, prod = 1;
        for (int k = 0; k < K; ++k) { prod *= (drow[k] == trow[k]) ? 1 : 0; na += prod; }
        s_na = na;
        out[OUT_NA + b] = na;
        int srow = slot[b];
        for (int jj = 0; jj < K; ++jj) {
            int idx = na + jj;
            int v = (idx < K) ? past_t[srow * K + idx] : trow[idx - K];
            out[OUT_NPT + b * K + jj] = v;
        }
        int tok0 = trow[na - 1];
        out[OUT_NNT + b * K1 + 0] = tok0;
        tok_ws[b] = tok0;
        for (int i = 0; i < K1; ++i) out[OUT_ACC + b * K1 + i] = trow[i];
    }
    __syncthreads();
    const int na = s_na;
    const float4* src = (const float4*)(hs + ((size_t)b * K1 + (na - 1)) * H);
    float4* dst = (float4*)(h_buf + (size_t)b * H);
    for (int k = threadIdx.x; k < H / 4; k += 256) dst[k] = src[k];
}

// ------------------------------------------------------------------
// Kernel C1: rms scales for both halves
__global__ void rms_scale_kernel(const int* __restrict__ tok_ws, const float* __restrict__ embed,
                                 const float* __restrict__ h_src, float* __restrict__ scales) {
    const int b = blockIdx.x, tid = threadIdx.x;
    const int tok = tok_ws[b];
    const float4* e4 = (const float4*)(embed + (size_t)tok * H);
    const float4* h4 = (const float4*)(h_src + (size_t)b * H);
    float se = 0.f, sh = 0.f;
#pragma unroll
    for (int r = 0; r < 4; ++r) {
        float4 e = e4[tid + r * 256];
        float4 h = h4[tid + r * 256];
        se += e.x * e.x + e.y * e.y + e.z * e.z + e.w * e.w;
        sh += h.x * h.x + h.y * h.y + h.z * h.z + h.w * h.w;
    }
    __shared__ float r1[256], r2[256];
    r1[tid] = se; r2[tid] = sh;
    __syncthreads();
    for (int s = 128; s > 0; s >>= 1) {
        if (tid < (unsigned)s) { r1[tid] += r1[tid + s]; r2[tid] += r2[tid + s]; }
        __syncthreads();
    }
    if (tid == 0) {
        scales[b]     = 1.0f / sqrtf(r1[0] * (1.0f / H) + 1e-6f);
        scales[64 + b] = 1.0f / sqrtf(r2[0] * (1.0f / H) + 1e-6f);
    }
}

// ------------------------------------------------------------------
// Kernel C2: build u_T[p][b] (p-major, b contiguous), rmsnorm applied. One block per 64-p tile.
__global__ void build_uT_kernel(const int* __restrict__ tok_ws, const float* __restrict__ embed,
                                const float* __restrict__ h_src, const float* __restrict__ scales,
                                float* __restrict__ u_T) {
    const int p0 = blockIdx.x * 64;  // 0..8128
    const int tid = threadIdx.x;
    __shared__ float T[64][65];
    const int pq = tid & 15;        // 16 float4 = 64 p
    const int brow = tid >> 4;      // 0..15
#pragma unroll
    for (int r = 0; r < 4; ++r) {
        const int b = brow + r * 16;
        const float* src;
        float sc;
        if (p0 < H) { src = embed + (size_t)tok_ws[b] * H + p0; sc = scales[b]; }
        else        { src = h_src + (size_t)b * H + (p0 - H);   sc = scales[64 + b]; }
        const float4 g = *(const float4*)(src + pq * 4);
        T[b][pq * 4 + 0] = g.x * sc;
        T[b][pq * 4 + 1] = g.y * sc;
        T[b][pq * 4 + 2] = g.z * sc;
        T[b][pq * 4 + 3] = g.w * sc;
    }
    __syncthreads();
    const int bq = tid & 15;        // 16 float4 = 64 b
    const int prow = tid >> 4;
#pragma unroll
    for (int r = 0; r < 4; ++r) {
        const int p = prow + r * 16;
        float4 o;
        o.x = T[bq * 4 + 0][p];
        o.y = T[bq * 4 + 1][p];
        o.z = T[bq * 4 + 2][p];
        o.w = T[bq * 4 + 3][p];
        *(float4*)(u_T + (size_t)(p0 + p) * B + bq * 4) = o;
    }
}

// ------------------------------------------------------------------
// Kernel D: GEMM1 partial. part[ks][o][b] = sum_{p in ks-range} W[p][o] * u_T[p][b]
// tile 256o x 64b, thread 4o x 16b. W is already k(p)-major -> direct LDS staging.
__global__ __launch_bounds__(256) void gemm1_tiled(const float* __restrict__ W,
                                                   const float* __restrict__ us,
                                                   float* __restrict__ part) {
    const int tid = threadIdx.x;
    const int o0g = blockIdx.x * 256;       // 16 tiles
    const int ks  = blockIdx.y;             // 32 splits
    const int kbase = ks * 256;
    __shared__ float Ws[32][256];
    const int tx = tid & 3;                 // b-group: b0 = tx*16
    const int ty = tid >> 2;                // 0..63 : o-quad
    const int b0 = tx * 16;
    float acc[4][16];
#pragma unroll
    for (int i = 0; i < 4; ++i)
#pragma unroll
        for (int j = 0; j < 16; ++j) acc[i][j] = 0.f;

    const int oq = tid & 63;                // staging: o-quad
    const int pr = tid >> 6;                // 0..3

    for (int ch = 0; ch < 8; ++ch) {
        const int p0 = kbase + ch * 32;
        // stage W[p0..p0+31][o0g..o0g+255] -> Ws[k][o], direct (no transpose needed)
#pragma unroll
        for (int r = 0; r < 8; ++r) {
            const int p = pr + r * 4;
            const float4 g = *(const float4*)(W + (size_t)(p0 + p) * H + o0g + oq * 4);
            *(float4*)(&Ws[p][oq * 4]) = g;
        }
        __syncthreads();
#pragma unroll 4
        for (int k = 0; k < 32; ++k) {
            const float* urow = us + (size_t)(p0 + k) * B + b0;
            const float4 xa = *(const float4*)(urow);
            const float4 xb = *(const float4*)(urow + 4);
            const float4 xc = *(const float4*)(urow + 8);
            const float4 xd = *(const float4*)(urow + 12);
            const float4 la = ((const float4*)&Ws[k][0])[ty];
            const float lv[4] = {la.x, la.y, la.z, la.w};
            const float xv[16] = {xa.x, xa.y, xa.z, xa.w, xb.x, xb.y, xb.z, xb.w,
                                  xc.x, xc.y, xc.z, xc.w, xd.x, xd.y, xd.z, xd.w};
#pragma unroll
            for (int vi = 0; vi < 4; ++vi)
#pragma unroll
                for (int bi = 0; bi < 16; ++bi)
                    acc[vi][bi] = fmaf(lv[vi], xv[bi], acc[vi][bi]);
        }
        __syncthreads();
    }
    // write part[ks][o][b]
#pragma unroll
    for (int vi = 0; vi < 4; ++vi) {
        float* d = part + ((size_t)ks * H + o0g + ty * 4 + vi) * B + b0;
        *(float4*)(d)      = make_float4(acc[vi][0],  acc[vi][1],  acc[vi][2],  acc[vi][3]);
        *(float4*)(d + 4)  = make_float4(acc[vi][4],  acc[vi][5],  acc[vi][6],  acc[vi][7]);
        *(float4*)(d + 8)  = make_float4(acc[vi][8],  acc[vi][9],  acc[vi][10], acc[vi][11]);
        *(float4*)(d + 12) = make_float4(acc[vi][12], acc[vi][13], acc[vi][14], acc[vi][15]);
    }
}

// ------------------------------------------------------------------
// Kernel E: reduce 32 gemm1 partials -> x_row [b][h] and xs [h][b]
__global__ void reduce1_kernel(const float* __restrict__ part, float* __restrict__ x_row,
                               float* __restrict__ xs) {
    const int flat = blockIdx.x * 256 + threadIdx.x;  // 0..262143
    const int o = flat >> 6, b = flat & 63;
    float s = 0.f;
#pragma unroll
    for (int ks = 0; ks < 32; ++ks) s += part[((size_t)ks * H + o) * B + b];
    x_row[(size_t)b * H + o] = s;
    xs[(size_t)o * B + b] = s;
}

// ------------------------------------------------------------------
// Kernel F: GEMM2 partial. part[ks][v][b] = sum_{h in ks-range} L[v][h] * xs[h][b]
// tile 256v x 64b, thread 4v x 16b. L is v-major -> transpose staging with XOR quad swizzle.
__global__ __launch_bounds__(256) void gemm2_tiled(const float* __restrict__ L,
                                                   const float* __restrict__ xs,
                                                   float* __restrict__ part) {
    const int tid = threadIdx.x;
    const int v0g = blockIdx.x * 256;       // 125 tiles
    const int ks  = blockIdx.y;             // 4 splits
    const int kbase = ks * 1024;
    __shared__ float Ls[32][256];
    const int tx = tid & 3;
    const int ty = tid >> 2;                // 0..63 : v-quad
    const int b0 = tx * 16;
    float acc[4][16];
#pragma unroll
    for (int i = 0; i < 4; ++i)
#pragma unroll
        for (int j = 0; j < 16; ++j) acc[i][j] = 0.f;

    const int kq  = tid & 7;                // staging: k-quad within chunk
    const int vr0 = tid >> 3;               // 0..31

    for (int ch = 0; ch < 32; ++ch) {
        const int k0 = kbase + ch * 32;
        // stage L[v0g+v][k0..k0+31] -> Ls[k][v], transposed, quad-swizzled: col quad = (v>>2)^kq
#pragma unroll
        for (int r = 0; r < 8; ++r) {
            const int v = vr0 + r * 32;
            const float4 g = *(const float4*)(L + (size_t)(v0g + v) * H + k0 + kq * 4);
            const int col = ((((v >> 2) ^ kq) << 2) | (v & 3));
            Ls[kq * 4 + 0][col] = g.x;
            Ls[kq * 4 + 1][col] = g.y;
            Ls[kq * 4 + 2][col] = g.z;
            Ls[kq * 4 + 3][col] = g.w;
        }
        __syncthreads();
#pragma unroll 4
        for (int k = 0; k < 32; ++k) {
            const float* xrow = xs + (size_t)(k0 + k) * B + b0;
            const float4 xa = *(const float4*)(xrow);
            const float4 xb = *(const float4*)(xrow + 4);
            const float4 xc = *(const float4*)(xrow + 8);
            const float4 xd = *(const float4*)(xrow + 12);
            const float4 la = ((const float4*)&Ls[k][0])[ty ^ (k >> 2)];
            const float lv[4] = {la.x, la.y, la.z, la.w};
            const float xv[16] = {xa.x, xa.y, xa.z, xa.w, xb.x, xb.y, xb.z, xb.w,
                                  xc.x, xc.y, xc.z, xc.w, xd.x, xd.y, xd.z, xd.w};
#pragma unroll
            for (int vi = 0; vi < 4; ++vi)
#pragma unroll
                for (int bi = 0; bi < 16; ++bi)
                    acc[vi][bi] = fmaf(lv[vi], xv[bi], acc[vi][bi]);
        }
        __syncthreads();
    }
    // write part[ks][v][b]
#pragma unroll
    for (int vi = 0; vi < 4; ++vi) {
        float* d = part + ((size_t)ks * V + v0g + ty * 4 + vi) * B + b0;
        *(float4*)(d)      = make_float4(acc[vi][0],  acc[vi][1],  acc[vi][2],  acc[vi][3]);
        *(float4*)(d + 4)  = make_float4(acc[vi][4],  acc[vi][5],  acc[vi][6],  acc[vi][7]);
        *(float4*)(d + 8)  = make_float4(acc[vi][8],  acc[vi][9],  acc[vi][10], acc[vi][11]);
        *(float4*)(d + 12) = make_float4(acc[vi][12], acc[vi][13], acc[vi][14], acc[vi][15]);
    }
}

// ------------------------------------------------------------------
// Kernel G: reduce 4 gemm2 partials + per-block argmax over a 640-v chunk.
__global__ void reduce2_kernel(const float* __restrict__ part, float* __restrict__ cand_val,
                               int* __restrict__ cand_idx) {
    const int blk = blockIdx.x;      // 0..49
    const int tid = threadIdx.x;
    const int b = tid & 63, vs = tid >> 6;
    const int v0 = blk * 640 + vs * 160;
    float bv = -INFINITY; int bi = 0x7fffffff;
    for (int i = 0; i < 160; ++i) {
        const int v = v0 + i;
        const size_t base = (size_t)v * B + b;
        const size_t stride = (size_t)V * B;
        float s = part[base] + part[stride + base] + part[2 * stride + base] + part[3 * stride + base];
        if (s > bv) { bv = s; bi = v; }   // ascending v => strict > keeps first index
    }
    __shared__ float sv[4][64];
    __shared__ int si[4][64];
    sv[vs][b] = bv; si[vs][b] = bi;
    __syncthreads();
    if (tid < 64) {
        float v0v = sv[0][tid]; int i0 = si[0][tid];
#pragma unroll
        for (int s2 = 1; s2 < 4; ++s2) {
            float ov = sv[s2][tid]; int oi = si[s2][tid];
            if (ov > v0v || (ov == v0v && oi < i0)) { v0v = ov; i0 = oi; }
        }
        cand_val[(size_t)blk * B + tid] = v0v;
        cand_idx[(size_t)blk * B + tid] = i0;
    }
}

// ------------------------------------------------------------------
// Kernel H: final argmax over 50 block candidates per b; writes tok + outputs for step j
__global__ void final_argmax_kernel(const float* __restrict__ cv, const int* __restrict__ ci,
                                    int* __restrict__ tok_ws, int* __restrict__ out, int j) {
    const int b = blockIdx.x, tid = threadIdx.x;  // 64 threads = 1 wave
    float bv = -INFINITY; int bi = 0x7fffffff;
    if (tid < 50) { bv = cv[(size_t)tid * B + b]; bi = ci[(size_t)tid * B + b]; }
    for (int off = 32; off > 0; off >>= 1) {
        float ov = __shfl_down(bv, off);
        int oi = __shfl_down(bi, off);
        if (ov > bv || (ov == bv && oi < bi)) { bv = ov; bi = oi; }
    }
    if (tid == 0) {
        tok_ws[b] = bi;
        out[OUT_NDT + b * K + j] = bi;
        out[OUT_NNT + b * K1 + 1 + j] = bi;
    }
}

// ------------------------------------------------------------------
extern "C" void kernel_launch(void* const* d_in, const int* in_sizes, int n_in,
                              void* d_out, int out_size, void* d_ws, size_t ws_size,
                              hipStream_t stream) {
    const float* logits  = (const float*)d_in[0];
    const float* hs      = (const float*)d_in[1];
    // d_in[2] past_hidden_pool: provably unused (num_accepted >= 1 => h always from hidden_states)
    const float* embed   = (const float*)d_in[3];
    const float* lm_head = (const float*)d_in[4];
    const float* mtp_fc  = (const float*)d_in[5];
    const int* draft     = (const int*)d_in[6];
    const int* past_t    = (const int*)d_in[7];
    const int* slot      = (const int*)d_in[8];
    int* out = (int*)d_out;

    char* ws = (char*)d_ws;
    int* target     = (int*)(ws + OFF_TARGET);
    int* tok_ws     = (int*)(ws + OFF_TOK);
    float* scales   = (float*)(ws + OFF_SCALE);
    float* h_buf    = (float*)(ws + OFF_HBUF);
    float* x_row    = (float*)(ws + OFF_XROW);
    float* xs       = (float*)(ws + OFF_XS);
    float* u_T      = (float*)(ws + OFF_UT);
    float* cand_val = (float*)(ws + OFF_CVAL);
    int* cand_idx   = (int*)(ws + OFF_CIDX);
    float* part     = (float*)(ws + OFF_PART);

    argmax_logits_kernel<<<B * K1, 256, 0, stream>>>(logits, target);
    accept_kernel<<<B, 256, 0, stream>>>(target, draft, past_t, slot, hs, out, tok_ws, h_buf);

    for (int j = 0; j < K; ++j) {
        const float* h_src = (j == 0) ? h_buf : x_row;
        rms_scale_kernel<<<B, 256, 0, stream>>>(tok_ws, embed, h_src, scales);
        build_uT_kernel<<<2 * H / 64, 256, 0, stream>>>(tok_ws, embed, h_src, scales, u_T);
        gemm1_tiled<<<dim3(16, 32), 256, 0, stream>>>(mtp_fc + (size_t)j * 2 * H * H, u_T, part);
        reduce1_kernel<<<H * B / 256, 256, 0, stream>>>(part, x_row, xs);
        gemm2_tiled<<<dim3(125, 4), 256, 0, stream>>>(lm_head, xs, part);
        reduce2_kernel<<<50, 256, 0, stream>>>(part, cand_val, cand_idx);
        final_argmax_kernel<<<B, 64, 0, stream>>>(cand_val, cand_idx, tok_ws, out, j);
    }
}

// Round 3
// 1198.562 us; speedup vs baseline: 4.2700x; 1.7904x over previous
//
#include <hip/hip_runtime.h>
#include <hip/hip_bf16.h>
#include <math.h>

#define B 64
#define K 3
#define H 4096
#define V 32000
#define K1 (K + 1)

// ---------------- workspace layout (bytes) ----------------
#define OFF_TARGET 0                       // 256 int
#define OFF_TOK    4096                    // 64 int
#define OFF_SCALE  8192                    // 128 float (sE[64], sH[64])
#define OFF_HBUF   16384                   // B*H float (1 MB)
#define OFF_XROW   (OFF_HBUF + (1u<<20))   // B*H float (1 MB), x row-major [b][h]
#define OFF_XS     (OFF_XROW + (1u<<20))   // H*B float (1 MB), x transposed [h][b]
#define OFF_UT     (OFF_XS + (1u<<20))     // 2H*B float (2 MB), u transposed [p][b]
#define OFF_CVAL   (OFF_UT + (2u<<20))     // 50*64 float
#define OFF_CIDX   (OFF_CVAL + 16384)      // 50*64 int
#define OFF_PART   (OFF_CIDX + 16384)      // max(32*H*B, 4*V*B) float = 33.6 MB

// out layout: accepted[256] | num_accepted[64] | next_draft[192] | next_new[256] | new_past_t[192]
#define OUT_ACC 0
#define OUT_NA  256
#define OUT_NDT 320
#define OUT_NNT 512
#define OUT_NPT 768

// ------------------------------------------------------------------
// Kernel A: row-wise argmax of logits (256 rows x 32000), first-index tie-break
__global__ void argmax_logits_kernel(const float* __restrict__ logits, int* __restrict__ target) {
    const int r = blockIdx.x;
    const float4* row = (const float4*)(logits + (size_t)r * V);
    float bv = -INFINITY;
    int bi = 0x7fffffff;
    for (int i4 = threadIdx.x; i4 < V / 4; i4 += 256) {
        float4 v = row[i4];
        int base = i4 * 4;
        if (v.x > bv) { bv = v.x; bi = base; }
        if (v.y > bv) { bv = v.y; bi = base + 1; }
        if (v.z > bv) { bv = v.z; bi = base + 2; }
        if (v.w > bv) { bv = v.w; bi = base + 3; }
    }
    __shared__ float sv[256];
    __shared__ int si[256];
    sv[threadIdx.x] = bv; si[threadIdx.x] = bi;
    __syncthreads();
    for (int s = 128; s > 0; s >>= 1) {
        if (threadIdx.x < (unsigned)s) {
            float ov = sv[threadIdx.x + s]; int oi = si[threadIdx.x + s];
            if (ov > sv[threadIdx.x] || (ov == sv[threadIdx.x] && oi < si[threadIdx.x])) {
                sv[threadIdx.x] = ov; si[threadIdx.x] = oi;
            }
        }
        __syncthreads();
    }
    if (threadIdx.x == 0) target[r] = si[0];
}

// ------------------------------------------------------------------
// Kernel B: acceptance logic + outputs + h gather
__global__ void accept_kernel(const int* __restrict__ target, const int* __restrict__ draft,
                              const int* __restrict__ past_t, const int* __restrict__ slot,
                              const float* __restrict__ hs, int* __restrict__ out,
                              int* __restrict__ tok_ws, float* __restrict__ h_buf) {
    const int b = blockIdx.x;
    __shared__ int s_na;
    if (threadIdx.x == 0) {
        const int* trow = target + b * K1;
        const int* drow = draft + b * K;
        int na = 1, prod = 1;
        for (int k = 0; k < K; ++k) { prod *= (drow[k] == trow[k]) ? 1 : 0; na += prod; }
        s_na = na;
        out[OUT_NA + b] = na;
        int srow = slot[b];
        for (int jj = 0; jj < K; ++jj) {
            int idx = na + jj;
            int v = (idx < K) ? past_t[srow * K + idx] : trow[idx - K];
            out[OUT_NPT + b * K + jj] = v;
        }
        int tok0 = trow[na - 1];
        out[OUT_NNT + b * K1 + 0] = tok0;
        tok_ws[b] = tok0;
        for (int i = 0; i < K1; ++i) out[OUT_ACC + b * K1 + i] = trow[i];
    }
    __syncthreads();
    const int na = s_na;
    const float4* src = (const float4*)(hs + ((size_t)b * K1 + (na - 1)) * H);
    float4* dst = (float4*)(h_buf + (size_t)b * H);
    for (int k = threadIdx.x; k < H / 4; k += 256) dst[k] = src[k];
}

// ------------------------------------------------------------------
// Kernel C1: rms scales for both halves
__global__ void rms_scale_kernel(const int* __restrict__ tok_ws, const float* __restrict__ embed,
                                 const float* __restrict__ h_src, float* __restrict__ scales) {
    const int b = blockIdx.x, tid = threadIdx.x;
    const int tok = tok_ws[b];
    const float4* e4 = (const float4*)(embed + (size_t)tok * H);
    const float4* h4 = (const float4*)(h_src + (size_t)b * H);
    float se = 0.f, sh = 0.f;
#pragma unroll
    for (int r = 0; r < 4; ++r) {
        float4 e = e4[tid + r * 256];
        float4 h = h4[tid + r * 256];
        se += e.x * e.x + e.y * e.y + e.z * e.z + e.w * e.w;
        sh += h.x * h.x + h.y * h.y + h.z * h.z + h.w * h.w;
    }
    __shared__ float r1[256], r2[256];
    r1[tid] = se; r2[tid] = sh;
    __syncthreads();
    for (int s = 128; s > 0; s >>= 1) {
        if (tid < (unsigned)s) { r1[tid] += r1[tid + s]; r2[tid] += r2[tid + s]; }
        __syncthreads();
    }
    if (tid == 0) {
        scales[b]      = 1.0f / sqrtf(r1[0] * (1.0f / H) + 1e-6f);
        scales[64 + b] = 1.0f / sqrtf(r2[0] * (1.0f / H) + 1e-6f);
    }
}

// ------------------------------------------------------------------
// Kernel C2: build u_T[p][b] (p-major, b contiguous), rmsnorm applied. One block per 64-p tile.
__global__ void build_uT_kernel(const int* __restrict__ tok_ws, const float* __restrict__ embed,
                                const float* __restrict__ h_src, const float* __restrict__ scales,
                                float* __restrict__ u_T) {
    const int p0 = blockIdx.x * 64;  // 0..8128
    const int tid = threadIdx.x;
    __shared__ float T[64][65];
    const int pq = tid & 15;        // 16 float4 = 64 p
    const int brow = tid >> 4;      // 0..15
#pragma unroll
    for (int r = 0; r < 4; ++r) {
        const int b = brow + r * 16;
        const float* src;
        float sc;
        if (p0 < H) { src = embed + (size_t)tok_ws[b] * H + p0; sc = scales[b]; }
        else        { src = h_src + (size_t)b * H + (p0 - H);   sc = scales[64 + b]; }
        const float4 g = *(const float4*)(src + pq * 4);
        T[b][pq * 4 + 0] = g.x * sc;
        T[b][pq * 4 + 1] = g.y * sc;
        T[b][pq * 4 + 2] = g.z * sc;
        T[b][pq * 4 + 3] = g.w * sc;
    }
    __syncthreads();
    const int bq = tid & 15;        // 16 float4 = 64 b
    const int prow = tid >> 4;
#pragma unroll
    for (int r = 0; r < 4; ++r) {
        const int p = prow + r * 16;
        float4 o;
        o.x = T[bq * 4 + 0][p];
        o.y = T[bq * 4 + 1][p];
        o.z = T[bq * 4 + 2][p];
        o.w = T[bq * 4 + 3][p];
        *(float4*)(u_T + (size_t)(p0 + p) * B + bq * 4) = o;
    }
}

// ------------------------------------------------------------------
// Kernel D: GEMM1 partial. part[ks][o][b] = sum_{p in ks-range} W[p][o] * u_T[p][b]
// Block tile 256o x 64b, 256 threads, thread tile 8o x 8b. W k(p)-major -> direct LDS staging.
// x-chunk (32p x 64b) staged in LDS too; register prefetch of next chunk.
__global__ __launch_bounds__(256, 2) void gemm1_tiled(const float* __restrict__ W,
                                                      const float* __restrict__ us,
                                                      float* __restrict__ part) {
    const int tid = threadIdx.x;
    const int o0g = blockIdx.x * 256;       // 16 tiles
    const int ks  = blockIdx.y;             // 32 splits
    const int kbase = ks * 256;             // 8 chunks of 32
    __shared__ float Ws[32][256];           // 32 KB
    __shared__ float Us[32][64];            // 8 KB

    const int g = tid >> 3;                 // o-group 0..31 (8 o each)
    const int h = tid & 7;                  // b-group 0..7  (8 b each)

    const int oq = tid & 63;                // staging: o-quad
    const int pr = tid >> 6;                // 0..3

    float acc[8][8];
#pragma unroll
    for (int i = 0; i < 8; ++i)
#pragma unroll
        for (int j = 0; j < 8; ++j) acc[i][j] = 0.f;

    float4 lreg[8], xreg[2];
    // prefetch chunk 0
    {
        const int p0 = kbase;
#pragma unroll
        for (int r = 0; r < 8; ++r)
            lreg[r] = *(const float4*)(W + (size_t)(p0 + pr + r * 4) * H + o0g + oq * 4);
        const float4* u4 = (const float4*)(us + (size_t)p0 * B);
        xreg[0] = u4[tid];
        xreg[1] = u4[tid + 256];
    }

    for (int ch = 0; ch < 8; ++ch) {
        __syncthreads();
        // regs -> LDS (direct layouts)
#pragma unroll
        for (int r = 0; r < 8; ++r)
            *(float4*)(&Ws[pr + r * 4][oq * 4]) = lreg[r];
        ((float4*)Us)[tid] = xreg[0];
        ((float4*)Us)[tid + 256] = xreg[1];
        __syncthreads();
        if (ch + 1 < 8) {
            const int p0 = kbase + (ch + 1) * 32;
#pragma unroll
            for (int r = 0; r < 8; ++r)
                lreg[r] = *(const float4*)(W + (size_t)(p0 + pr + r * 4) * H + o0g + oq * 4);
            const float4* u4 = (const float4*)(us + (size_t)p0 * B);
            xreg[0] = u4[tid];
            xreg[1] = u4[tid + 256];
        }
#pragma unroll 4
        for (int k = 0; k < 32; ++k) {
            const float4* lr = (const float4*)&Ws[k][0];
            const float4 a0 = lr[2 * g];
            const float4 a1 = lr[2 * g + 1];
            const float4* xr = (const float4*)&Us[k][0];
            const float4 x0 = xr[2 * h];
            const float4 x1 = xr[2 * h + 1];
            const float av[8] = {a0.x, a0.y, a0.z, a0.w, a1.x, a1.y, a1.z, a1.w};
            const float xv[8] = {x0.x, x0.y, x0.z, x0.w, x1.x, x1.y, x1.z, x1.w};
#pragma unroll
            for (int vi = 0; vi < 8; ++vi)
#pragma unroll
                for (int bi = 0; bi < 8; ++bi)
                    acc[vi][bi] = fmaf(av[vi], xv[bi], acc[vi][bi]);
        }
    }
    // write part[ks][o][b]
#pragma unroll
    for (int vi = 0; vi < 8; ++vi) {
        float* d = part + ((size_t)ks * H + o0g + g * 8 + vi) * B + h * 8;
        *(float4*)(d)     = make_float4(acc[vi][0], acc[vi][1], acc[vi][2], acc[vi][3]);
        *(float4*)(d + 4) = make_float4(acc[vi][4], acc[vi][5], acc[vi][6], acc[vi][7]);
    }
}

// ------------------------------------------------------------------
// Kernel E: reduce 32 gemm1 partials -> x_row [b][h] and xs [h][b]
__global__ void reduce1_kernel(const float* __restrict__ part, float* __restrict__ x_row,
                               float* __restrict__ xs) {
    const int flat = blockIdx.x * 256 + threadIdx.x;  // 0..262143
    const int o = flat >> 6, b = flat & 63;
    float s = 0.f;
#pragma unroll
    for (int ks = 0; ks < 32; ++ks) s += part[((size_t)ks * H + o) * B + b];
    x_row[(size_t)b * H + o] = s;
    xs[(size_t)o * B + b] = s;
}

// ------------------------------------------------------------------
// Kernel F: GEMM2 partial. part[ks][v][b] = sum_{h in ks-range} L[v][h] * xs[h][b]
// Block tile 256v x 64b, 256 threads, thread tile 8v x 8b.
// L is v-major -> transpose staging with XOR quad swizzle; x-chunk in LDS; reg prefetch.
__global__ __launch_bounds__(256, 2) void gemm2_tiled(const float* __restrict__ L,
                                                      const float* __restrict__ xs,
                                                      float* __restrict__ part) {
    const int tid = threadIdx.x;
    const int v0g = blockIdx.x * 256;       // 125 tiles
    const int ks  = blockIdx.y;             // 4 splits
    const int kbase = ks * 1024;            // 32 chunks of 32
    __shared__ float Ls[32][256];           // 32 KB
    __shared__ float Xs[32][64];            // 8 KB

    const int g = tid >> 3;                 // v-group 0..31 (8 v each)
    const int h = tid & 7;                  // b-group 0..7  (8 b each)

    const int kq  = tid & 7;                // staging: k-quad within chunk
    const int vr0 = tid >> 3;               // 0..31

    float acc[8][8];
#pragma unroll
    for (int i = 0; i < 8; ++i)
#pragma unroll
        for (int j = 0; j < 8; ++j) acc[i][j] = 0.f;

    float4 lreg[8], xreg[2];
    // prefetch chunk 0
    {
        const int k0 = kbase;
#pragma unroll
        for (int r = 0; r < 8; ++r)
            lreg[r] = *(const float4*)(L + (size_t)(v0g + vr0 + r * 32) * H + k0 + kq * 4);
        const float4* x4 = (const float4*)(xs + (size_t)k0 * B);
        xreg[0] = x4[tid];
        xreg[1] = x4[tid + 256];
    }

    for (int ch = 0; ch < 32; ++ch) {
        __syncthreads();
        // regs -> LDS: transpose with quad swizzle col_quad = (v>>2) ^ kq
#pragma unroll
        for (int r = 0; r < 8; ++r) {
            const int v = vr0 + r * 32;
            const int col = ((((v >> 2) ^ kq) << 2) | (v & 3));
            Ls[kq * 4 + 0][col] = lreg[r].x;
            Ls[kq * 4 + 1][col] = lreg[r].y;
            Ls[kq * 4 + 2][col] = lreg[r].z;
            Ls[kq * 4 + 3][col] = lreg[r].w;
        }
        ((float4*)Xs)[tid] = xreg[0];
        ((float4*)Xs)[tid + 256] = xreg[1];
        __syncthreads();
        if (ch + 1 < 32) {
            const int k0 = kbase + (ch + 1) * 32;
#pragma unroll
            for (int r = 0; r < 8; ++r)
                lreg[r] = *(const float4*)(L + (size_t)(v0g + vr0 + r * 32) * H + k0 + kq * 4);
            const float4* x4 = (const float4*)(xs + (size_t)k0 * B);
            xreg[0] = x4[tid];
            xreg[1] = x4[tid + 256];
        }
#pragma unroll 4
        for (int k = 0; k < 32; ++k) {
            const int srow = k >> 2;
            const float4* lr = (const float4*)&Ls[k][0];
            const float4 a0 = lr[(2 * g) ^ srow];
            const float4 a1 = lr[(2 * g + 1) ^ srow];
            const float4* xr = (const float4*)&Xs[k][0];
            const float4 x0 = xr[2 * h];
            const float4 x1 = xr[2 * h + 1];
            const float av[8] = {a0.x, a0.y, a0.z, a0.w, a1.x, a1.y, a1.z, a1.w};
            const float xv[8] = {x0.x, x0.y, x0.z, x0.w, x1.x, x1.y, x1.z, x1.w};
#pragma unroll
            for (int vi = 0; vi < 8; ++vi)
#pragma unroll
                for (int bi = 0; bi < 8; ++bi)
                    acc[vi][bi] = fmaf(av[vi], xv[bi], acc[vi][bi]);
        }
    }
    // write part[ks][v][b]
#pragma unroll
    for (int vi = 0; vi < 8; ++vi) {
        float* d = part + ((size_t)ks * V + v0g + g * 8 + vi) * B + h * 8;
        *(float4*)(d)     = make_float4(acc[vi][0], acc[vi][1], acc[vi][2], acc[vi][3]);
        *(float4*)(d + 4) = make_float4(acc[vi][4], acc[vi][5], acc[vi][6], acc[vi][7]);
    }
}

// ------------------------------------------------------------------
// Kernel G: reduce 4 gemm2 partials + per-block argmax over a 640-v chunk.
__global__ void reduce2_kernel(const float* __restrict__ part, float* __restrict__ cand_val,
                               int* __restrict__ cand_idx) {
    const int blk = blockIdx.x;      // 0..49
    const int tid = threadIdx.x;
    const int b = tid & 63, vs = tid >> 6;
    const int v0 = blk * 640 + vs * 160;
    float bv = -INFINITY; int bi = 0x7fffffff;
    for (int i = 0; i < 160; ++i) {
        const int v = v0 + i;
        const size_t base = (size_t)v * B + b;
        const size_t stride = (size_t)V * B;
        float s = part[base] + part[stride + base] + part[2 * stride + base] + part[3 * stride + base];
        if (s > bv) { bv = s; bi = v; }   // ascending v => strict > keeps first index
    }
    __shared__ float sv[4][64];
    __shared__ int si[4][64];
    sv[vs][b] = bv; si[vs][b] = bi;
    __syncthreads();
    if (tid < 64) {
        float v0v = sv[0][tid]; int i0 = si[0][tid];
#pragma unroll
        for (int s2 = 1; s2 < 4; ++s2) {
            float ov = sv[s2][tid]; int oi = si[s2][tid];
            if (ov > v0v || (ov == v0v && oi < i0)) { v0v = ov; i0 = oi; }
        }
        cand_val[(size_t)blk * B + tid] = v0v;
        cand_idx[(size_t)blk * B + tid] = i0;
    }
}

// ------------------------------------------------------------------
// Kernel H: final argmax over 50 block candidates per b; writes tok + outputs for step j
__global__ void final_argmax_kernel(const float* __restrict__ cv, const int* __restrict__ ci,
                                    int* __restrict__ tok_ws, int* __restrict__ out, int j) {
    const int b = blockIdx.x, tid = threadIdx.x;  // 64 threads = 1 wave
    float bv = -INFINITY; int bi = 0x7fffffff;
    if (tid < 50) { bv = cv[(size_t)tid * B + b]; bi = ci[(size_t)tid * B + b]; }
    for (int off = 32; off > 0; off >>= 1) {
        float ov = __shfl_down(bv, off);
        int oi = __shfl_down(bi, off);
        if (ov > bv || (ov == bv && oi < bi)) { bv = ov; bi = oi; }
    }
    if (tid == 0) {
        tok_ws[b] = bi;
        out[OUT_NDT + b * K + j] = bi;
        out[OUT_NNT + b * K1 + 1 + j] = bi;
    }
}

// ------------------------------------------------------------------
extern "C" void kernel_launch(void* const* d_in, const int* in_sizes, int n_in,
                              void* d_out, int out_size, void* d_ws, size_t ws_size,
                              hipStream_t stream) {
    const float* logits  = (const float*)d_in[0];
    const float* hs      = (const float*)d_in[1];
    // d_in[2] past_hidden_pool: provably unused (num_accepted >= 1 => h always from hidden_states)
    const float* embed   = (const float*)d_in[3];
    const float* lm_head = (const float*)d_in[4];
    const float* mtp_fc  = (const float*)d_in[5];
    const int* draft     = (const int*)d_in[6];
    const int* past_t    = (const int*)d_in[7];
    const int* slot      = (const int*)d_in[8];
    int* out = (int*)d_out;

    char* ws = (char*)d_ws;
    int* target     = (int*)(ws + OFF_TARGET);
    int* tok_ws     = (int*)(ws + OFF_TOK);
    float* scales   = (float*)(ws + OFF_SCALE);
    float* h_buf    = (float*)(ws + OFF_HBUF);
    float* x_row    = (float*)(ws + OFF_XROW);
    float* xs       = (float*)(ws + OFF_XS);
    float* u_T      = (float*)(ws + OFF_UT);
    float* cand_val = (float*)(ws + OFF_CVAL);
    int* cand_idx   = (int*)(ws + OFF_CIDX);
    float* part     = (float*)(ws + OFF_PART);

    argmax_logits_kernel<<<B * K1, 256, 0, stream>>>(logits, target);
    accept_kernel<<<B, 256, 0, stream>>>(target, draft, past_t, slot, hs, out, tok_ws, h_buf);

    for (int j = 0; j < K; ++j) {
        const float* h_src = (j == 0) ? h_buf : x_row;
        rms_scale_kernel<<<B, 256, 0, stream>>>(tok_ws, embed, h_src, scales);
        build_uT_kernel<<<2 * H / 64, 256, 0, stream>>>(tok_ws, embed, h_src, scales, u_T);
        gemm1_tiled<<<dim3(16, 32), 256, 0, stream>>>(mtp_fc + (size_t)j * 2 * H * H, u_T, part);
        reduce1_kernel<<<H * B / 256, 256, 0, stream>>>(part, x_row, xs);
        gemm2_tiled<<<dim3(125, 4), 256, 0, stream>>>(lm_head, xs, part);
        reduce2_kernel<<<50, 256, 0, stream>>>(part, cand_val, cand_idx);
        final_argmax_kernel<<<B, 64, 0, stream>>>(cand_val, cand_idx, tok_ws, out, j);
    }
}

// Round 4
// 944.128 us; speedup vs baseline: 5.4207x; 1.2695x over previous
//
#include <hip/hip_runtime.h>
#include <hip/hip_bf16.h>
#include <math.h>

#define B 64
#define K 3
#define H 4096
#define V 32000
#define K1 (K + 1)

typedef short bf16x8_t __attribute__((ext_vector_type(8)));
typedef float f32x4_t __attribute__((ext_vector_type(4)));

// ---------------- workspace layout (bytes) ----------------
#define OFF_TARGET  0                      // 256 int
#define OFF_TOK     1024                   // 64 int
#define OFF_CNT     2048                   // 64 int
#define OFF_THR     4096                   // 64 float
#define OFF_SCALE   8192                   // 128 float
#define OFF_TILEMAX 16384                  // 125*64 float = 32000 B
#define OFF_CAND    65536                  // 64*128 int = 32 KB
#define OFF_HBUF    (1u << 20)             // B*H float (1 MB)
#define OFF_XROW    (2u << 20)             // B*H float, x row-major [b][h]
#define OFF_XS      (3u << 20)             // H*B float, x transposed [h][b]
#define OFF_UT      (4u << 20)             // 2H*B float (2 MB)
#define OFF_XF      (6u << 20)             // x bf16 frag layout (512 KB)
#define OFF_DLOGA   (7u << 20)             // V*B float approx logits (8 MB)
#define OFF_PART    (16u << 20)            // 32 MB: gemm1 parts / gemm2 parts (time-shared)
#define OFF_LF      (48u << 20)            // lm_head bf16 frag layout (262 MB)

// out layout: accepted[256] | num_accepted[64] | next_draft[192] | next_new[256] | new_past_t[192]
#define OUT_ACC 0
#define OUT_NA  256
#define OUT_NDT 320
#define OUT_NNT 512
#define OUT_NPT 768

#define DELTA 0.75f
#define CAP   128

__device__ __forceinline__ unsigned short f2bf(float f) {
    unsigned int u = __float_as_uint(f);
    u += 0x7fffu + ((u >> 16) & 1u);       // round-to-nearest-even
    return (unsigned short)(u >> 16);
}

// ------------------------------------------------------------------
// Kernel A: row-wise argmax of logits (256 rows x 32000), first-index tie-break
__global__ void argmax_logits_kernel(const float* __restrict__ logits, int* __restrict__ target) {
    const int r = blockIdx.x;
    const float4* row = (const float4*)(logits + (size_t)r * V);
    float bv = -INFINITY;
    int bi = 0x7fffffff;
    for (int i4 = threadIdx.x; i4 < V / 4; i4 += 256) {
        float4 v = row[i4];
        int base = i4 * 4;
        if (v.x > bv) { bv = v.x; bi = base; }
        if (v.y > bv) { bv = v.y; bi = base + 1; }
        if (v.z > bv) { bv = v.z; bi = base + 2; }
        if (v.w > bv) { bv = v.w; bi = base + 3; }
    }
    __shared__ float sv[256];
    __shared__ int si[256];
    sv[threadIdx.x] = bv; si[threadIdx.x] = bi;
    __syncthreads();
    for (int s = 128; s > 0; s >>= 1) {
        if (threadIdx.x < (unsigned)s) {
            float ov = sv[threadIdx.x + s]; int oi = si[threadIdx.x + s];
            if (ov > sv[threadIdx.x] || (ov == sv[threadIdx.x] && oi < si[threadIdx.x])) {
                sv[threadIdx.x] = ov; si[threadIdx.x] = oi;
            }
        }
        __syncthreads();
    }
    if (threadIdx.x == 0) target[r] = si[0];
}

// ------------------------------------------------------------------
// Kernel B: acceptance logic + outputs + h gather
__global__ void accept_kernel(const int* __restrict__ target, const int* __restrict__ draft,
                              const int* __restrict__ past_t, const int* __restrict__ slot,
                              const float* __restrict__ hs, int* __restrict__ out,
                              int* __restrict__ tok_ws, float* __restrict__ h_buf) {
    const int b = blockIdx.x;
    __shared__ int s_na;
    if (threadIdx.x == 0) {
        const int* trow = target + b * K1;
        const int* drow = draft + b * K;
        int na = 1, prod = 1;
        for (int k = 0; k < K; ++k) { prod *= (drow[k] == trow[k]) ? 1 : 0; na += prod; }
        s_na = na;
        out[OUT_NA + b] = na;
        int srow = slot[b];
        for (int jj = 0; jj < K; ++jj) {
            int idx = na + jj;
            int v = (idx < K) ? past_t[srow * K + idx] : trow[idx - K];
            out[OUT_NPT + b * K + jj] = v;
        }
        int tok0 = trow[na - 1];
        out[OUT_NNT + b * K1 + 0] = tok0;
        tok_ws[b] = tok0;
        for (int i = 0; i < K1; ++i) out[OUT_ACC + b * K1 + i] = trow[i];
    }
    __syncthreads();
    const int na = s_na;
    const float4* src = (const float4*)(hs + ((size_t)b * K1 + (na - 1)) * H);
    float4* dst = (float4*)(h_buf + (size_t)b * H);
    for (int k = threadIdx.x; k < H / 4; k += 256) dst[k] = src[k];
}

// ------------------------------------------------------------------
// Kernel LF: convert lm_head fp32 [V][H] -> bf16 MFMA-A-fragment layout.
// frag (vc,kc): lane l elem i holds L[vc*16 + (l&15)][kc*32 + 8*(l>>4) + i]
// stored at Lf[((vc*128 + kc)*64 + l)*8 + i]
__global__ __launch_bounds__(256) void convert_lf(const float* __restrict__ L, unsigned short* __restrict__ Lf) {
    const int k0 = blockIdx.x * 128;   // 32 blocks
    const int v0 = blockIdx.y * 64;    // 500 blocks
    __shared__ float T[64][132];
    const int t = threadIdx.x;
    const int vl = t >> 5, k4 = t & 31;
#pragma unroll
    for (int r = 0; r < 8; ++r) {
        const int v = vl + r * 8;
        const float4 g = *(const float4*)(L + (size_t)(v0 + v) * H + k0 + k4 * 4);
        T[v][k4 * 4 + 0] = g.x;
        T[v][k4 * 4 + 1] = g.y;
        T[v][k4 * 4 + 2] = g.z;
        T[v][k4 * 4 + 3] = g.w;
    }
    __syncthreads();
#pragma unroll
    for (int s = 0; s < 4; ++s) {
        const int slot = t + s * 256;       // 0..1023
        const int f = slot >> 6, l = slot & 63;
        const int vcl = f >> 2, kcl = f & 3;
        const int row = vcl * 16 + (l & 15);
        const int col = kcl * 32 + (l >> 4) * 8;
        unsigned int u[4];
#pragma unroll
        for (int p = 0; p < 4; ++p)
            u[p] = (unsigned int)f2bf(T[row][col + 2 * p]) | ((unsigned int)f2bf(T[row][col + 2 * p + 1]) << 16);
        const size_t vc = (size_t)(v0 >> 4) + vcl;
        const size_t kc = (size_t)(k0 >> 5) + kcl;
        *(uint4*)(Lf + ((vc * 128 + kc) * 64 + l) * 8) = make_uint4(u[0], u[1], u[2], u[3]);
    }
}

// ------------------------------------------------------------------
// Kernel C1: rms scales for both halves
__global__ void rms_scale_kernel(const int* __restrict__ tok_ws, const float* __restrict__ embed,
                                 const float* __restrict__ h_src, float* __restrict__ scales) {
    const int b = blockIdx.x, tid = threadIdx.x;
    const int tok = tok_ws[b];
    const float4* e4 = (const float4*)(embed + (size_t)tok * H);
    const float4* h4 = (const float4*)(h_src + (size_t)b * H);
    float se = 0.f, sh = 0.f;
#pragma unroll
    for (int r = 0; r < 4; ++r) {
        float4 e = e4[tid + r * 256];
        float4 h = h4[tid + r * 256];
        se += e.x * e.x + e.y * e.y + e.z * e.z + e.w * e.w;
        sh += h.x * h.x + h.y * h.y + h.z * h.z + h.w * h.w;
    }
    __shared__ float r1[256], r2[256];
    r1[tid] = se; r2[tid] = sh;
    __syncthreads();
    for (int s = 128; s > 0; s >>= 1) {
        if (tid < (unsigned)s) { r1[tid] += r1[tid + s]; r2[tid] += r2[tid + s]; }
        __syncthreads();
    }
    if (tid == 0) {
        scales[b]      = 1.0f / sqrtf(r1[0] * (1.0f / H) + 1e-6f);
        scales[64 + b] = 1.0f / sqrtf(r2[0] * (1.0f / H) + 1e-6f);
    }
}

// ------------------------------------------------------------------
// Kernel C2: build u_T[p][b] (p-major, b contiguous), rmsnorm applied.
__global__ void build_uT_kernel(const int* __restrict__ tok_ws, const float* __restrict__ embed,
                                const float* __restrict__ h_src, const float* __restrict__ scales,
                                float* __restrict__ u_T) {
    const int p0 = blockIdx.x * 64;
    const int tid = threadIdx.x;
    __shared__ float T[64][65];
    const int pq = tid & 15;
    const int brow = tid >> 4;
#pragma unroll
    for (int r = 0; r < 4; ++r) {
        const int b = brow + r * 16;
        const float* src;
        float sc;
        if (p0 < H) { src = embed + (size_t)tok_ws[b] * H + p0; sc = scales[b]; }
        else        { src = h_src + (size_t)b * H + (p0 - H);   sc = scales[64 + b]; }
        const float4 g = *(const float4*)(src + pq * 4);
        T[b][pq * 4 + 0] = g.x * sc;
        T[b][pq * 4 + 1] = g.y * sc;
        T[b][pq * 4 + 2] = g.z * sc;
        T[b][pq * 4 + 3] = g.w * sc;
    }
    __syncthreads();
    const int bq = tid & 15;
    const int prow = tid >> 4;
#pragma unroll
    for (int r = 0; r < 4; ++r) {
        const int p = prow + r * 16;
        float4 o;
        o.x = T[bq * 4 + 0][p];
        o.y = T[bq * 4 + 1][p];
        o.z = T[bq * 4 + 2][p];
        o.w = T[bq * 4 + 3][p];
        *(float4*)(u_T + (size_t)(p0 + p) * B + bq * 4) = o;
    }
}

// ------------------------------------------------------------------
// Kernel D: GEMM1 (fp32, exact). part[ks][o][b] = sum_{p in ks} W[p][o] * u_T[p][b]
__global__ __launch_bounds__(256, 2) void gemm1_tiled(const float* __restrict__ W,
                                                      const float* __restrict__ us,
                                                      float* __restrict__ part) {
    const int tid = threadIdx.x;
    const int o0g = blockIdx.x * 256;
    const int ks  = blockIdx.y;
    const int kbase = ks * 256;
    __shared__ float Ws[32][256];
    __shared__ float Us[32][64];

    const int g = tid >> 3;
    const int h = tid & 7;
    const int oq = tid & 63;
    const int pr = tid >> 6;

    float acc[8][8];
#pragma unroll
    for (int i = 0; i < 8; ++i)
#pragma unroll
        for (int j = 0; j < 8; ++j) acc[i][j] = 0.f;

    float4 lreg[8], xreg[2];
    {
        const int p0 = kbase;
#pragma unroll
        for (int r = 0; r < 8; ++r)
            lreg[r] = *(const float4*)(W + (size_t)(p0 + pr + r * 4) * H + o0g + oq * 4);
        const float4* u4 = (const float4*)(us + (size_t)p0 * B);
        xreg[0] = u4[tid];
        xreg[1] = u4[tid + 256];
    }

    for (int ch = 0; ch < 8; ++ch) {
        __syncthreads();
#pragma unroll
        for (int r = 0; r < 8; ++r)
            *(float4*)(&Ws[pr + r * 4][oq * 4]) = lreg[r];
        ((float4*)Us)[tid] = xreg[0];
        ((float4*)Us)[tid + 256] = xreg[1];
        __syncthreads();
        if (ch + 1 < 8) {
            const int p0 = kbase + (ch + 1) * 32;
#pragma unroll
            for (int r = 0; r < 8; ++r)
                lreg[r] = *(const float4*)(W + (size_t)(p0 + pr + r * 4) * H + o0g + oq * 4);
            const float4* u4 = (const float4*)(us + (size_t)p0 * B);
            xreg[0] = u4[tid];
            xreg[1] = u4[tid + 256];
        }
#pragma unroll 4
        for (int k = 0; k < 32; ++k) {
            const float4* lr = (const float4*)&Ws[k][0];
            const float4 a0 = lr[2 * g];
            const float4 a1 = lr[2 * g + 1];
            const float4* xr = (const float4*)&Us[k][0];
            const float4 x0 = xr[2 * h];
            const float4 x1 = xr[2 * h + 1];
            const float av[8] = {a0.x, a0.y, a0.z, a0.w, a1.x, a1.y, a1.z, a1.w};
            const float xv[8] = {x0.x, x0.y, x0.z, x0.w, x1.x, x1.y, x1.z, x1.w};
#pragma unroll
            for (int vi = 0; vi < 8; ++vi)
#pragma unroll
                for (int bi = 0; bi < 8; ++bi)
                    acc[vi][bi] = fmaf(av[vi], xv[bi], acc[vi][bi]);
        }
    }
#pragma unroll
    for (int vi = 0; vi < 8; ++vi) {
        float* d = part + ((size_t)ks * H + o0g + g * 8 + vi) * B + h * 8;
        *(float4*)(d)     = make_float4(acc[vi][0], acc[vi][1], acc[vi][2], acc[vi][3]);
        *(float4*)(d + 4) = make_float4(acc[vi][4], acc[vi][5], acc[vi][6], acc[vi][7]);
    }
}

// ------------------------------------------------------------------
// Kernel E: reduce 32 gemm1 partials -> x_row [b][h] and xs [h][b]
__global__ void reduce1_kernel(const float* __restrict__ part, float* __restrict__ x_row,
                               float* __restrict__ xs) {
    const int flat = blockIdx.x * 256 + threadIdx.x;
    const int o = flat >> 6, b = flat & 63;
    float s = 0.f;
#pragma unroll
    for (int ks = 0; ks < 32; ++ks) s += part[((size_t)ks * H + o) * B + b];
    x_row[(size_t)b * H + o] = s;
    xs[(size_t)o * B + b] = s;
}

// ------------------------------------------------------------------
// Kernel XF: x (fp32 [h][b]) -> bf16 MFMA-B-fragment layout.
// frag (kc,g): lane l elem i holds x[kc*32 + 8*(l>>4) + i][g*16 + (l&15)]
__global__ void build_xf_kernel(const float* __restrict__ xs, unsigned short* __restrict__ xf) {
    const int kc = blockIdx.x;             // 128
    const int t = threadIdx.x;
    const int g = t >> 6, l = t & 63;
    const int krow = kc * 32 + (l >> 4) * 8;
    const int b = g * 16 + (l & 15);
    unsigned int u[4];
#pragma unroll
    for (int p = 0; p < 4; ++p) {
        const float a = xs[(size_t)(krow + 2 * p) * B + b];
        const float c = xs[(size_t)(krow + 2 * p + 1) * B + b];
        u[p] = (unsigned int)f2bf(a) | ((unsigned int)f2bf(c) << 16);
    }
    *(uint4*)(xf + ((size_t)(kc * 4 + g) * 64 + l) * 8) = make_uint4(u[0], u[1], u[2], u[3]);
}

// ------------------------------------------------------------------
// Kernel F: GEMM2 approx via bf16 MFMA. part[ks][v][b], ks=0..3 (k-split of H into 32-kc chunks).
// Block: 256v x 64b, 4 waves; wave w owns v-frags vc0..vc0+3, all 4 b-frags.
__global__ __launch_bounds__(256, 2) void gemm2_mfma(const unsigned short* __restrict__ Lf_,
                                                     const unsigned short* __restrict__ xf_,
                                                     float* __restrict__ part) {
    const int tid = threadIdx.x;
    const int lane = tid & 63;
    const int w = tid >> 6;
    const int vc0 = blockIdx.x * 16 + w * 4;
    const int ks = blockIdx.y;
    const int kcb = ks * 32;

    const bf16x8_t* A = (const bf16x8_t*)Lf_;
    const bf16x8_t* Bx = (const bf16x8_t*)xf_;

    const f32x4_t z = {0.f, 0.f, 0.f, 0.f};
    f32x4_t acc[4][4];
#pragma unroll
    for (int a = 0; a < 4; ++a)
#pragma unroll
        for (int g = 0; g < 4; ++g) acc[a][g] = z;

    const size_t aBase = ((size_t)vc0 * 128 + kcb) * 64 + lane;   // + a*8192 + dkc*64
    const size_t bBase = ((size_t)kcb * 4) * 64 + lane;           // + (dkc*4+g)*64

    bf16x8_t a0[4], a1[4], b0[4], b1[4];
#pragma unroll
    for (int a = 0; a < 4; ++a) a0[a] = A[aBase + (size_t)a * 8192];
#pragma unroll
    for (int g = 0; g < 4; ++g) b0[g] = Bx[bBase + (size_t)g * 64];
#pragma unroll
    for (int a = 0; a < 4; ++a) a1[a] = A[aBase + (size_t)a * 8192 + 64];
#pragma unroll
    for (int g = 0; g < 4; ++g) b1[g] = Bx[bBase + (size_t)(4 + g) * 64];

    for (int dkc = 0; dkc < 32; dkc += 2) {
#pragma unroll
        for (int a = 0; a < 4; ++a)
#pragma unroll
            for (int g = 0; g < 4; ++g)
                acc[a][g] = __builtin_amdgcn_mfma_f32_16x16x32_bf16(a0[a], b0[g], acc[a][g], 0, 0, 0);
        if (dkc + 2 < 32) {
#pragma unroll
            for (int a = 0; a < 4; ++a) a0[a] = A[aBase + (size_t)a * 8192 + (size_t)(dkc + 2) * 64];
#pragma unroll
            for (int g = 0; g < 4; ++g) b0[g] = Bx[bBase + (size_t)((dkc + 2) * 4 + g) * 64];
        }
#pragma unroll
        for (int a = 0; a < 4; ++a)
#pragma unroll
            for (int g = 0; g < 4; ++g)
                acc[a][g] = __builtin_amdgcn_mfma_f32_16x16x32_bf16(a1[a], b1[g], acc[a][g], 0, 0, 0);
        if (dkc + 3 < 32) {
#pragma unroll
            for (int a = 0; a < 4; ++a) a1[a] = A[aBase + (size_t)a * 8192 + (size_t)(dkc + 3) * 64];
#pragma unroll
            for (int g = 0; g < 4; ++g) b1[g] = Bx[bBase + (size_t)((dkc + 3) * 4 + g) * 64];
        }
    }

    // write part[ks][v][b]: D layout col(b)=lane&15, row(v)=(lane>>4)*4+reg
    const int bcol = lane & 15;
    const int rgrp = lane >> 4;
    float* dst = part + (size_t)ks * V * B;
#pragma unroll
    for (int a = 0; a < 4; ++a) {
        const int vbase = (vc0 + a) * 16 + rgrp * 4;
#pragma unroll
        for (int g = 0; g < 4; ++g) {
#pragma unroll
            for (int r = 0; r < 4; ++r)
                dst[(size_t)(vbase + r) * B + g * 16 + bcol] = acc[a][g][r];
        }
    }
}

// ------------------------------------------------------------------
// Kernel G: combine 4 k-split parts -> dlogA[v][b]; per-256v-tile per-b max.
__global__ void combine_max_kernel(const float* __restrict__ part, float* __restrict__ dlogA,
                                   float* __restrict__ tileMax) {
    const int v0 = blockIdx.x * 256;
    const int t = threadIdx.x;
    const size_t stride = (size_t)V * B;
    float m = -INFINITY;
    for (int i = t; i < 256 * 64; i += 256) {
        const int vl = i >> 6, b = i & 63;   // b == t&63 for all i
        const size_t idx = (size_t)(v0 + vl) * B + b;
        const float s = part[idx] + part[stride + idx] + part[2 * stride + idx] + part[3 * stride + idx];
        dlogA[idx] = s;
        m = fmaxf(m, s);
    }
    __shared__ float tmx[4][64];
    tmx[t >> 6][t & 63] = m;
    __syncthreads();
    if (t < 64) {
        const float mm = fmaxf(fmaxf(tmx[0][t], tmx[1][t]), fmaxf(tmx[2][t], tmx[3][t]));
        tileMax[(size_t)blockIdx.x * 64 + t] = mm;
    }
}

// ------------------------------------------------------------------
// Kernel T: per-b global threshold = max - DELTA; zero candidate counters.
__global__ void thr_kernel(const float* __restrict__ tileMax, float* __restrict__ thr,
                           int* __restrict__ cnt) {
    const int t = threadIdx.x;   // 64
    float m = -INFINITY;
    for (int i = 0; i < V / 256; ++i) m = fmaxf(m, tileMax[i * 64 + t]);
    thr[t] = m - DELTA;
    cnt[t] = 0;
}

// ------------------------------------------------------------------
// Kernel CO: collect candidates with approx >= thr[b].
__global__ void collect_kernel(const float* __restrict__ dlogA, const float* __restrict__ thr,
                               int* __restrict__ cnt, int* __restrict__ cand) {
    const int v0 = blockIdx.x * 256;
    for (int i = threadIdx.x; i < 256 * 64; i += 256) {
        const int vl = i >> 6, b = i & 63;
        const float val = dlogA[(size_t)(v0 + vl) * B + b];
        if (val >= thr[b]) {
            const int slot = atomicAdd(&cnt[b], 1);
            if (slot < CAP) cand[b * CAP + slot] = v0 + vl;
        }
    }
}

// ------------------------------------------------------------------
// Kernel R: exact fp32 rescore of candidates + deterministic argmax (val desc, idx asc).
__global__ __launch_bounds__(256) void rescore_kernel(const int* __restrict__ cnt, const int* __restrict__ cand,
                                                      const float* __restrict__ L, const float* __restrict__ x_row,
                                                      int* __restrict__ tok_ws, int* __restrict__ out, int j) {
    const int b = blockIdx.x;
    const int lane = threadIdx.x & 63, w = threadIdx.x >> 6;
    const int n = min(cnt[b], CAP);
    const float* xr = x_row + (size_t)b * H;
    float bv = -INFINITY;
    int bi = 0x7fffffff;
    for (int c = w; c < n; c += 4) {
        const int v = cand[b * CAP + c];
        const float* Lr = L + (size_t)v * H;
        float s = 0.f;
#pragma unroll 8
        for (int t = 0; t < 64; ++t) s = fmaf(Lr[lane + 64 * t], xr[lane + 64 * t], s);
#pragma unroll
        for (int off = 32; off >= 1; off >>= 1) s += __shfl_xor(s, off);
        if (s > bv || (s == bv && v < bi)) { bv = s; bi = v; }
    }
    __shared__ float sv[4];
    __shared__ int si[4];
    if (lane == 0) { sv[w] = bv; si[w] = bi; }
    __syncthreads();
    if (threadIdx.x == 0) {
        float fv = sv[0]; int fi = si[0];
        for (int q = 1; q < 4; ++q)
            if (sv[q] > fv || (sv[q] == fv && si[q] < fi)) { fv = sv[q]; fi = si[q]; }
        tok_ws[b] = fi;
        out[OUT_NDT + b * K + j] = fi;
        out[OUT_NNT + b * K1 + 1 + j] = fi;
    }
}

// ------------------------------------------------------------------
extern "C" void kernel_launch(void* const* d_in, const int* in_sizes, int n_in,
                              void* d_out, int out_size, void* d_ws, size_t ws_size,
                              hipStream_t stream) {
    const float* logits  = (const float*)d_in[0];
    const float* hs      = (const float*)d_in[1];
    // d_in[2] past_hidden_pool: provably unused (num_accepted >= 1)
    const float* embed   = (const float*)d_in[3];
    const float* lm_head = (const float*)d_in[4];
    const float* mtp_fc  = (const float*)d_in[5];
    const int* draft     = (const int*)d_in[6];
    const int* past_t    = (const int*)d_in[7];
    const int* slot      = (const int*)d_in[8];
    int* out = (int*)d_out;

    char* ws = (char*)d_ws;
    int* target       = (int*)(ws + OFF_TARGET);
    int* tok_ws       = (int*)(ws + OFF_TOK);
    int* cnt          = (int*)(ws + OFF_CNT);
    float* thr        = (float*)(ws + OFF_THR);
    float* scales     = (float*)(ws + OFF_SCALE);
    float* tileMax    = (float*)(ws + OFF_TILEMAX);
    int* cand         = (int*)(ws + OFF_CAND);
    float* h_buf      = (float*)(ws + OFF_HBUF);
    float* x_row      = (float*)(ws + OFF_XROW);
    float* xs         = (float*)(ws + OFF_XS);
    float* u_T        = (float*)(ws + OFF_UT);
    unsigned short* xf = (unsigned short*)(ws + OFF_XF);
    float* dlogA      = (float*)(ws + OFF_DLOGA);
    float* part       = (float*)(ws + OFF_PART);
    unsigned short* Lf = (unsigned short*)(ws + OFF_LF);

    convert_lf<<<dim3(H / 128, V / 64), 256, 0, stream>>>(lm_head, Lf);
    argmax_logits_kernel<<<B * K1, 256, 0, stream>>>(logits, target);
    accept_kernel<<<B, 256, 0, stream>>>(target, draft, past_t, slot, hs, out, tok_ws, h_buf);

    for (int j = 0; j < K; ++j) {
        const float* h_src = (j == 0) ? h_buf : x_row;
        rms_scale_kernel<<<B, 256, 0, stream>>>(tok_ws, embed, h_src, scales);
        build_uT_kernel<<<2 * H / 64, 256, 0, stream>>>(tok_ws, embed, h_src, scales, u_T);
        gemm1_tiled<<<dim3(16, 32), 256, 0, stream>>>(mtp_fc + (size_t)j * 2 * H * H, u_T, part);
        reduce1_kernel<<<H * B / 256, 256, 0, stream>>>(part, x_row, xs);
        build_xf_kernel<<<H / 32, 256, 0, stream>>>(xs, xf);
        gemm2_mfma<<<dim3(V / 256, 4), 256, 0, stream>>>(Lf, xf, part);
        combine_max_kernel<<<V / 256, 256, 0, stream>>>(part, dlogA, tileMax);
        thr_kernel<<<1, 64, 0, stream>>>(tileMax, thr, cnt);
        collect_kernel<<<V / 256, 256, 0, stream>>>(dlogA, thr, cnt, cand);
        rescore_kernel<<<B, 256, 0, stream>>>(cnt, cand, lm_head, x_row, tok_ws, out, j);
    }
}

// Round 8
// 941.011 us; speedup vs baseline: 5.4386x; 1.0033x over previous
//
#include <hip/hip_runtime.h>
#include <hip/hip_bf16.h>
#include <math.h>

#define B 64
#define K 3
#define H 4096
#define V 32000
#define K1 (K + 1)

typedef short bf16x8_t __attribute__((ext_vector_type(8)));
typedef float f32x4_t __attribute__((ext_vector_type(4)));

// ---------------- workspace layout (bytes) ----------------
#define OFF_TARGET  0                      // 256 int
#define OFF_TOK     1024                   // 64 int
#define OFF_CNT     2048                   // 64 int
#define OFF_THR     4096                   // 64 float
#define OFF_SCALE   8192                   // 128 float
#define OFF_CAND    16384                  // 64*128 int = 32 KB
#define OFF_TILEMAX 65536                  // 500*64 float = 128 KB
#define OFF_HBUF    (1u << 20)             // B*H float (1 MB)
#define OFF_XROW    (2u << 20)             // B*H float, x row-major [b][h]
#define OFF_UF      (3u << 20)             // u 3-way bf16 split frags (3 MB)
#define OFF_XF      (6u << 20)             // x bf16 frag layout (512 KB)
#define OFF_DLOGA   (7u << 20)             // V*B float approx logits (8.2 MB)
#define OFF_PART    (16u << 20)            // 16 ks * H * B float = 16.8 MB
#define OFF_LF      (48u << 20)            // lm_head bf16 frag layout (262 MB)

// out layout: accepted[256] | num_accepted[64] | next_draft[192] | next_new[256] | new_past_t[192]
#define OUT_ACC 0
#define OUT_NA  256
#define OUT_NDT 320
#define OUT_NNT 512
#define OUT_NPT 768

#define DELTA 0.75f
#define CAP   128

__device__ __forceinline__ unsigned short f2bf(float f) {
    unsigned int u = __float_as_uint(f);
    u += 0x7fffu + ((u >> 16) & 1u);       // round-to-nearest-even
    return (unsigned short)(u >> 16);
}
__device__ __forceinline__ float bf2f(unsigned short h) {
    return __uint_as_float(((unsigned int)h) << 16);
}
__device__ __forceinline__ uint4 mku4(const unsigned short* p) {
    return make_uint4((unsigned)p[0] | ((unsigned)p[1] << 16),
                      (unsigned)p[2] | ((unsigned)p[3] << 16),
                      (unsigned)p[4] | ((unsigned)p[5] << 16),
                      (unsigned)p[6] | ((unsigned)p[7] << 16));
}
__device__ __forceinline__ bf16x8_t mkfrag(const unsigned short* p) {
    union { uint4 q; bf16x8_t v; } u;
    u.q = mku4(p);
    return u.v;
}

// ------------------------------------------------------------------
// Kernel A: row-wise argmax of logits (256 rows x 32000), first-index tie-break
__global__ void argmax_logits_kernel(const float* __restrict__ logits, int* __restrict__ target) {
    const int r = blockIdx.x;
    const float4* row = (const float4*)(logits + (size_t)r * V);
    float bv = -INFINITY;
    int bi = 0x7fffffff;
    for (int i4 = threadIdx.x; i4 < V / 4; i4 += 256) {
        float4 v = row[i4];
        int base = i4 * 4;
        if (v.x > bv) { bv = v.x; bi = base; }
        if (v.y > bv) { bv = v.y; bi = base + 1; }
        if (v.z > bv) { bv = v.z; bi = base + 2; }
        if (v.w > bv) { bv = v.w; bi = base + 3; }
    }
    __shared__ float sv[256];
    __shared__ int si[256];
    sv[threadIdx.x] = bv; si[threadIdx.x] = bi;
    __syncthreads();
    for (int s = 128; s > 0; s >>= 1) {
        if (threadIdx.x < (unsigned)s) {
            float ov = sv[threadIdx.x + s]; int oi = si[threadIdx.x + s];
            if (ov > sv[threadIdx.x] || (ov == sv[threadIdx.x] && oi < si[threadIdx.x])) {
                sv[threadIdx.x] = ov; si[threadIdx.x] = oi;
            }
        }
        __syncthreads();
    }
    if (threadIdx.x == 0) target[r] = si[0];
}

// ------------------------------------------------------------------
// Kernel B: acceptance logic + outputs + h gather
__global__ void accept_kernel(const int* __restrict__ target, const int* __restrict__ draft,
                              const int* __restrict__ past_t, const int* __restrict__ slot,
                              const float* __restrict__ hs, int* __restrict__ out,
                              int* __restrict__ tok_ws, float* __restrict__ h_buf) {
    const int b = blockIdx.x;
    __shared__ int s_na;
    if (threadIdx.x == 0) {
        const int* trow = target + b * K1;
        const int* drow = draft + b * K;
        int na = 1, prod = 1;
        for (int k = 0; k < K; ++k) { prod *= (drow[k] == trow[k]) ? 1 : 0; na += prod; }
        s_na = na;
        out[OUT_NA + b] = na;
        int srow = slot[b];
        for (int jj = 0; jj < K; ++jj) {
            int idx = na + jj;
            int v = (idx < K) ? past_t[srow * K + idx] : trow[idx - K];
            out[OUT_NPT + b * K + jj] = v;
        }
        int tok0 = trow[na - 1];
        out[OUT_NNT + b * K1 + 0] = tok0;
        tok_ws[b] = tok0;
        for (int i = 0; i < K1; ++i) out[OUT_ACC + b * K1 + i] = trow[i];
    }
    __syncthreads();
    const int na = s_na;
    const float4* src = (const float4*)(hs + ((size_t)b * K1 + (na - 1)) * H);
    float4* dst = (float4*)(h_buf + (size_t)b * H);
    for (int k = threadIdx.x; k < H / 4; k += 256) dst[k] = src[k];
}

// ------------------------------------------------------------------
// Kernel LF: convert lm_head fp32 [V][H] -> bf16 MFMA-A-fragment layout.
// frag (vc,kc): lane l elem i holds L[vc*16 + (l&15)][kc*32 + 8*(l>>4) + i]
__global__ __launch_bounds__(256) void convert_lf(const float* __restrict__ L, unsigned short* __restrict__ Lf) {
    const int k0 = blockIdx.x * 128;   // 32 blocks
    const int v0 = blockIdx.y * 64;    // 500 blocks
    __shared__ float T[64][132];
    const int t = threadIdx.x;
    const int vl = t >> 5, k4 = t & 31;
#pragma unroll
    for (int r = 0; r < 8; ++r) {
        const int v = vl + r * 8;
        const float4 g = *(const float4*)(L + (size_t)(v0 + v) * H + k0 + k4 * 4);
        T[v][k4 * 4 + 0] = g.x;
        T[v][k4 * 4 + 1] = g.y;
        T[v][k4 * 4 + 2] = g.z;
        T[v][k4 * 4 + 3] = g.w;
    }
    __syncthreads();
#pragma unroll
    for (int s = 0; s < 4; ++s) {
        const int slot = t + s * 256;       // 0..1023
        const int f = slot >> 6, l = slot & 63;
        const int vcl = f >> 2, kcl = f & 3;
        const int row = vcl * 16 + (l & 15);
        const int col = kcl * 32 + (l >> 4) * 8;
        unsigned int u[4];
#pragma unroll
        for (int p = 0; p < 4; ++p)
            u[p] = (unsigned int)f2bf(T[row][col + 2 * p]) | ((unsigned int)f2bf(T[row][col + 2 * p + 1]) << 16);
        const size_t vc = (size_t)(v0 >> 4) + vcl;
        const size_t kc = (size_t)(k0 >> 5) + kcl;
        *(uint4*)(Lf + ((vc * 128 + kc) * 64 + l) * 8) = make_uint4(u[0], u[1], u[2], u[3]);
    }
}

// ------------------------------------------------------------------
// Kernel C1: rms scales for both halves
__global__ void rms_scale_kernel(const int* __restrict__ tok_ws, const float* __restrict__ embed,
                                 const float* __restrict__ h_src, float* __restrict__ scales) {
    const int b = blockIdx.x, tid = threadIdx.x;
    const int tok = tok_ws[b];
    const float4* e4 = (const float4*)(embed + (size_t)tok * H);
    const float4* h4 = (const float4*)(h_src + (size_t)b * H);
    float se = 0.f, sh = 0.f;
#pragma unroll
    for (int r = 0; r < 4; ++r) {
        float4 e = e4[tid + r * 256];
        float4 h = h4[tid + r * 256];
        se += e.x * e.x + e.y * e.y + e.z * e.z + e.w * e.w;
        sh += h.x * h.x + h.y * h.y + h.z * h.z + h.w * h.w;
    }
    __shared__ float r1[256], r2[256];
    r1[tid] = se; r2[tid] = sh;
    __syncthreads();
    for (int s = 128; s > 0; s >>= 1) {
        if (tid < (unsigned)s) { r1[tid] += r1[tid + s]; r2[tid] += r2[tid + s]; }
        __syncthreads();
    }
    if (tid == 0) {
        scales[b]      = 1.0f / sqrtf(r1[0] * (1.0f / H) + 1e-6f);
        scales[64 + b] = 1.0f / sqrtf(r2[0] * (1.0f / H) + 1e-6f);
    }
}

// ------------------------------------------------------------------
// Kernel C2: build u 3-way bf16 split directly in MFMA-B-fragment layout.
// uf frag idx = ((chunk*4 + bc)*3 + s)*64 + lane ; elem i = u[chunk*32 + 8*(l>>4)+i][bc*16 + (l&15)]
__global__ __launch_bounds__(256) void build_uf_kernel(const int* __restrict__ tok_ws, const float* __restrict__ embed,
                                                       const float* __restrict__ h_src, const float* __restrict__ scales,
                                                       unsigned short* __restrict__ uf) {
    const int c = blockIdx.x;           // 0..255 (p-chunk of 32)
    const int tid = threadIdx.x;
    const int g = tid >> 6, l = tid & 63;
    const int g4 = l >> 4, li = l & 15;
    const int b = g * 16 + li;
    unsigned short h0[8], h1[8], h2[8];
    const float* src;
    float sc;
    if (c < H / 32) { src = embed + (size_t)tok_ws[b] * H + c * 32; sc = scales[b]; }
    else            { src = h_src + (size_t)b * H + (c - H / 32) * 32; sc = scales[64 + b]; }
#pragma unroll
    for (int i = 0; i < 8; ++i) {
        const float a = src[8 * g4 + i] * sc;
        const unsigned short hh = f2bf(a);
        const float r = a - bf2f(hh);
        const unsigned short mm = f2bf(r);
        const float r2 = r - bf2f(mm);
        h0[i] = hh; h1[i] = mm; h2[i] = f2bf(r2);
    }
    unsigned short* dst = uf + (size_t)(((c * 4 + g) * 3) * 64 + l) * 8;
    *(uint4*)(dst)        = mku4(h0);
    *(uint4*)(dst + 512)  = mku4(h1);
    *(uint4*)(dst + 1024) = mku4(h2);
}

// ------------------------------------------------------------------
// Kernel D: GEMM1 via split-bf16 MFMA (6 passes, near-fp32-exact).
// part[ks][o][b] = sum_{p in ks-range} W[p][o] * u[p][b]
// grid (32 o-blocks of 128, 16 k-splits of 512); 4 waves; wave owns 2 vc (32 o).
__global__ __launch_bounds__(256) void gemm1_mfma(const float* __restrict__ W,
                                                  const unsigned short* __restrict__ uf,
                                                  float* __restrict__ part) {
    const int tid = threadIdx.x, lane = tid & 63, w = tid >> 6;
    const int bx = blockIdx.x;
    const int ks = blockIdx.y;
    const int vc0 = bx * 8 + w * 2;
    const int g4 = lane >> 4, li = lane & 15;
    const int kbase = ks * 512;

    const bf16x8_t* Bu = (const bf16x8_t*)uf;
    const f32x4_t z = {0.f, 0.f, 0.f, 0.f};
    f32x4_t acc[2][4];
#pragma unroll
    for (int v2 = 0; v2 < 2; ++v2)
#pragma unroll
        for (int bc = 0; bc < 4; ++bc) acc[v2][bc] = z;

    const float* Wb = W + (size_t)(kbase + 8 * g4) * H + vc0 * 16 + li;

    float acur[2][8], anxt[2][8];
    // prologue: A chunk 0
#pragma unroll
    for (int v2 = 0; v2 < 2; ++v2)
#pragma unroll
        for (int i = 0; i < 8; ++i) acur[v2][i] = Wb[(size_t)i * H + v2 * 16];

    for (int c = 0; c < 16; ++c) {
        const int cg = ks * 16 + c;
        // B frags for this chunk (L2-resident)
        bf16x8_t br[12];
#pragma unroll
        for (int f = 0; f < 12; ++f) br[f] = Bu[((size_t)cg * 12 + f) * 64 + lane];
        // prefetch next A chunk
        if (c + 1 < 16) {
#pragma unroll
            for (int v2 = 0; v2 < 2; ++v2)
#pragma unroll
                for (int i = 0; i < 8; ++i) anxt[v2][i] = Wb[(size_t)((c + 1) * 32 + i) * H + v2 * 16];
        }
        // in-register 3-way split of A
        bf16x8_t A0[2], A1[2], A2[2];
#pragma unroll
        for (int v2 = 0; v2 < 2; ++v2) {
            unsigned short s0[8], s1[8], s2[8];
#pragma unroll
            for (int i = 0; i < 8; ++i) {
                const float a = acur[v2][i];
                const unsigned short hh = f2bf(a);
                const float r = a - bf2f(hh);
                const unsigned short mm = f2bf(r);
                const float r2 = r - bf2f(mm);
                s0[i] = hh; s1[i] = mm; s2[i] = f2bf(r2);
            }
            A0[v2] = mkfrag(s0); A1[v2] = mkfrag(s1); A2[v2] = mkfrag(s2);
        }
        // 6-pass MFMA (i+j<=2)
#pragma unroll
        for (int v2 = 0; v2 < 2; ++v2) {
#pragma unroll
            for (int bc = 0; bc < 4; ++bc) {
                f32x4_t t = acc[v2][bc];
                t = __builtin_amdgcn_mfma_f32_16x16x32_bf16(A0[v2], br[bc * 3 + 0], t, 0, 0, 0);
                t = __builtin_amdgcn_mfma_f32_16x16x32_bf16(A0[v2], br[bc * 3 + 1], t, 0, 0, 0);
                t = __builtin_amdgcn_mfma_f32_16x16x32_bf16(A1[v2], br[bc * 3 + 0], t, 0, 0, 0);
                t = __builtin_amdgcn_mfma_f32_16x16x32_bf16(A0[v2], br[bc * 3 + 2], t, 0, 0, 0);
                t = __builtin_amdgcn_mfma_f32_16x16x32_bf16(A1[v2], br[bc * 3 + 1], t, 0, 0, 0);
                t = __builtin_amdgcn_mfma_f32_16x16x32_bf16(A2[v2], br[bc * 3 + 0], t, 0, 0, 0);
                acc[v2][bc] = t;
            }
        }
#pragma unroll
        for (int v2 = 0; v2 < 2; ++v2)
#pragma unroll
            for (int i = 0; i < 8; ++i) acur[v2][i] = anxt[v2][i];
    }
    // write part[ks][o][b]: D layout col(b)=lane&15, row(o)=(lane>>4)*4+reg
#pragma unroll
    for (int v2 = 0; v2 < 2; ++v2) {
        const int obase = (vc0 + v2) * 16 + g4 * 4;
#pragma unroll
        for (int bc = 0; bc < 4; ++bc)
#pragma unroll
            for (int r = 0; r < 4; ++r)
                part[((size_t)ks * H + obase + r) * B + bc * 16 + li] = acc[v2][bc][r];
    }
}

// ------------------------------------------------------------------
// Kernel E: reduce 16 gemm1 partials -> x_row [b][h] AND xf (bf16 B-frag layout).
__global__ __launch_bounds__(256) void reduce1_fused(const float* __restrict__ part, float* __restrict__ x_row,
                                                     unsigned short* __restrict__ xf) {
    const int kc = blockIdx.x;          // 0..127 (h-chunk of 32)
    const int tid = threadIdx.x;
    const int g = tid >> 6, l = tid & 63;
    const int g4 = l >> 4, li = l & 15;
    const int b = g * 16 + li;
    __shared__ float X[32][65];
    float sv[8];
#pragma unroll
    for (int i = 0; i < 8; ++i) {
        const int o = kc * 32 + 8 * g4 + i;
        float s = 0.f;
#pragma unroll
        for (int ks = 0; ks < 16; ++ks) s += part[((size_t)ks * H + o) * B + b];
        sv[i] = s;
        X[8 * g4 + i][b] = s;
    }
    unsigned int u[4];
#pragma unroll
    for (int p = 0; p < 4; ++p)
        u[p] = (unsigned int)f2bf(sv[2 * p]) | ((unsigned int)f2bf(sv[2 * p + 1]) << 16);
    *(uint4*)(xf + (size_t)((kc * 4 + g) * 64 + l) * 8) = make_uint4(u[0], u[1], u[2], u[3]);
    __syncthreads();
    const int b2 = tid >> 2, oq = tid & 3;
    float4 o0, o1;
    o0.x = X[oq * 8 + 0][b2]; o0.y = X[oq * 8 + 1][b2]; o0.z = X[oq * 8 + 2][b2]; o0.w = X[oq * 8 + 3][b2];
    o1.x = X[oq * 8 + 4][b2]; o1.y = X[oq * 8 + 5][b2]; o1.z = X[oq * 8 + 6][b2]; o1.w = X[oq * 8 + 7][b2];
    float* dst = x_row + (size_t)b2 * H + kc * 32 + oq * 8;
    *(float4*)(dst) = o0;
    *(float4*)(dst + 4) = o1;
}

// ------------------------------------------------------------------
// Kernel F: GEMM2 approx via bf16 MFMA, full-H per block, writes dlogA + per-block tileMax.
// grid 500 blocks; wave w owns vc = bx*4+w (16 v-rows), all 4 b-frags, kc 0..127.
__global__ __launch_bounds__(256) void gemm2_mfma(const unsigned short* __restrict__ Lf_,
                                                  const unsigned short* __restrict__ xf_,
                                                  float* __restrict__ dlogA,
                                                  float* __restrict__ tileMax) {
    const int tid = threadIdx.x, lane = tid & 63, w = tid >> 6;
    const int vc = blockIdx.x * 4 + w;
    const bf16x8_t* A = (const bf16x8_t*)Lf_;
    const bf16x8_t* Bx = (const bf16x8_t*)xf_;
    const size_t aBase = (size_t)vc * 128 * 64 + lane;

    const f32x4_t z = {0.f, 0.f, 0.f, 0.f};
    f32x4_t acc[4];
#pragma unroll
    for (int g = 0; g < 4; ++g) acc[g] = z;

    bf16x8_t ar[4];
    bf16x8_t br[4][4];
#pragma unroll
    for (int d = 0; d < 4; ++d) {
        ar[d] = A[aBase + (size_t)d * 64];
#pragma unroll
        for (int g = 0; g < 4; ++g) br[d][g] = Bx[(size_t)(d * 4 + g) * 64 + lane];
    }

    for (int kc = 0; kc < 128; kc += 4) {
#pragma unroll
        for (int d = 0; d < 4; ++d) {
#pragma unroll
            for (int g = 0; g < 4; ++g)
                acc[g] = __builtin_amdgcn_mfma_f32_16x16x32_bf16(ar[d], br[d][g], acc[g], 0, 0, 0);
            const int nk = kc + 4 + d;
            if (nk < 128) {
                ar[d] = A[aBase + (size_t)nk * 64];
#pragma unroll
                for (int g = 0; g < 4; ++g) br[d][g] = Bx[(size_t)(nk * 4 + g) * 64 + lane];
            }
        }
    }

    // per-b max over this block's 64 v
    const int li = lane & 15, g4 = lane >> 4;
    float m[4];
#pragma unroll
    for (int g = 0; g < 4; ++g) {
        m[g] = fmaxf(fmaxf(acc[g][0], acc[g][1]), fmaxf(acc[g][2], acc[g][3]));
        m[g] = fmaxf(m[g], __shfl_xor(m[g], 16));
        m[g] = fmaxf(m[g], __shfl_xor(m[g], 32));
    }
    // write dlogA[v][b]
#pragma unroll
    for (int g = 0; g < 4; ++g) {
        const int vbase = vc * 16 + g4 * 4;
#pragma unroll
        for (int r = 0; r < 4; ++r)
            dlogA[(size_t)(vbase + r) * B + g * 16 + li] = acc[g][r];
    }
    __shared__ float sm[4][4][16];
    if (lane < 16) {
#pragma unroll
        for (int g = 0; g < 4; ++g) sm[w][g][lane] = m[g];
    }
    __syncthreads();
    if (tid < 64) {
        const int gg = tid >> 4, ii = tid & 15;
        const float mm = fmaxf(fmaxf(sm[0][gg][ii], sm[1][gg][ii]), fmaxf(sm[2][gg][ii], sm[3][gg][ii]));
        tileMax[(size_t)blockIdx.x * B + tid] = mm;
    }
}

// ------------------------------------------------------------------
// Kernel T: per-b global threshold = max - DELTA; zero candidate counters.
__global__ void thr_kernel(const float* __restrict__ tileMax, float* __restrict__ thr,
                           int* __restrict__ cnt) {
    const int t = threadIdx.x;   // 64
    float m = -INFINITY;
    for (int i = 0; i < 500; ++i) m = fmaxf(m, tileMax[i * B + t]);
    thr[t] = m - DELTA;
    cnt[t] = 0;
}

// ------------------------------------------------------------------
// Kernel CO: collect candidates with approx >= thr[b].
__global__ void collect_kernel(const float* __restrict__ dlogA, const float* __restrict__ thr,
                               int* __restrict__ cnt, int* __restrict__ cand) {
    const int v0 = blockIdx.x * 256;
    for (int i = threadIdx.x; i < 256 * 64; i += 256) {
        const int vl = i >> 6, b = i & 63;
        const float val = dlogA[(size_t)(v0 + vl) * B + b];
        if (val >= thr[b]) {
            const int slot = atomicAdd(&cnt[b], 1);
            if (slot < CAP) cand[b * CAP + slot] = v0 + vl;
        }
    }
}

// ------------------------------------------------------------------
// Kernel R: exact fp32 rescore of candidates + deterministic argmax (val desc, idx asc).
__global__ __launch_bounds__(256) void rescore_kernel(const int* __restrict__ cnt, const int* __restrict__ cand,
                                                      const float* __restrict__ L, const float* __restrict__ x_row,
                                                      int* __restrict__ tok_ws, int* __restrict__ out, int j) {
    const int b = blockIdx.x;
    const int lane = threadIdx.x & 63, w = threadIdx.x >> 6;
    const int n = min(cnt[b], CAP);
    const float* xr = x_row + (size_t)b * H;
    float bv = -INFINITY;
    int bi = 0x7fffffff;
    for (int c = w; c < n; c += 4) {
        const int v = cand[b * CAP + c];
        const float* Lr = L + (size_t)v * H;
        float s = 0.f;
#pragma unroll 8
        for (int t = 0; t < 64; ++t) s = fmaf(Lr[lane + 64 * t], xr[lane + 64 * t], s);
#pragma unroll
        for (int off = 32; off >= 1; off >>= 1) s += __shfl_xor(s, off);
        if (s > bv || (s == bv && v < bi)) { bv = s; bi = v; }
    }
    __shared__ float sv[4];
    __shared__ int si[4];
    if (lane == 0) { sv[w] = bv; si[w] = bi; }
    __syncthreads();
    if (threadIdx.x == 0) {
        float fv = sv[0]; int fi = si[0];
        for (int q = 1; q < 4; ++q)
            if (sv[q] > fv || (sv[q] == fv && si[q] < fi)) { fv = sv[q]; fi = si[q]; }
        tok_ws[b] = fi;
        out[OUT_NDT + b * K + j] = fi;
        out[OUT_NNT + b * K1 + 1 + j] = fi;
    }
}

// ------------------------------------------------------------------
extern "C" void kernel_launch(void* const* d_in, const int* in_sizes, int n_in,
                              void* d_out, int out_size, void* d_ws, size_t ws_size,
                              hipStream_t stream) {
    const float* logits  = (const float*)d_in[0];
    const float* hs      = (const float*)d_in[1];
    // d_in[2] past_hidden_pool: provably unused (num_accepted >= 1)
    const float* embed   = (const float*)d_in[3];
    const float* lm_head = (const float*)d_in[4];
    const float* mtp_fc  = (const float*)d_in[5];
    const int* draft     = (const int*)d_in[6];
    const int* past_t    = (const int*)d_in[7];
    const int* slot      = (const int*)d_in[8];
    int* out = (int*)d_out;

    char* ws = (char*)d_ws;
    int* target        = (int*)(ws + OFF_TARGET);
    int* tok_ws        = (int*)(ws + OFF_TOK);
    int* cnt           = (int*)(ws + OFF_CNT);
    float* thr         = (float*)(ws + OFF_THR);
    float* scales      = (float*)(ws + OFF_SCALE);
    int* cand          = (int*)(ws + OFF_CAND);
    float* tileMax     = (float*)(ws + OFF_TILEMAX);
    float* h_buf       = (float*)(ws + OFF_HBUF);
    float* x_row       = (float*)(ws + OFF_XROW);
    unsigned short* uf = (unsigned short*)(ws + OFF_UF);
    unsigned short* xf = (unsigned short*)(ws + OFF_XF);
    float* dlogA       = (float*)(ws + OFF_DLOGA);
    float* part        = (float*)(ws + OFF_PART);
    unsigned short* Lf = (unsigned short*)(ws + OFF_LF);

    convert_lf<<<dim3(H / 128, V / 64), 256, 0, stream>>>(lm_head, Lf);
    argmax_logits_kernel<<<B * K1, 256, 0, stream>>>(logits, target);
    accept_kernel<<<B, 256, 0, stream>>>(target, draft, past_t, slot, hs, out, tok_ws, h_buf);

    for (int j = 0; j < K; ++j) {
        const float* h_src = (j == 0) ? h_buf : x_row;
        rms_scale_kernel<<<B, 256, 0, stream>>>(tok_ws, embed, h_src, scales);
        build_uf_kernel<<<2 * H / 32, 256, 0, stream>>>(tok_ws, embed, h_src, scales, uf);
        gemm1_mfma<<<dim3(32, 16), 256, 0, stream>>>(mtp_fc + (size_t)j * 2 * H * H, uf, part);
        reduce1_fused<<<H / 32, 256, 0, stream>>>(part, x_row, xf);
        gemm2_mfma<<<V / 64, 256, 0, stream>>>(Lf, xf, dlogA, tileMax);
        thr_kernel<<<1, 64, 0, stream>>>(tileMax, thr, cnt);
        collect_kernel<<<V / 256, 256, 0, stream>>>(dlogA, thr, cnt, cand);
        rescore_kernel<<<B, 256, 0, stream>>>(cnt, cand, lm_head, x_row, tok_ws, out, j);
    }
}

// Round 9
// 637.233 us; speedup vs baseline: 8.0313x; 1.4767x over previous
//
#include <hip/hip_runtime.h>
#include <hip/hip_bf16.h>
#include <math.h>

#define B 64
#define K 3
#define H 4096
#define V 32000
#define K1 (K + 1)

typedef short bf16x8_t __attribute__((ext_vector_type(8)));
typedef float f32x4_t __attribute__((ext_vector_type(4)));

// ---------------- workspace layout (bytes) ----------------
#define OFF_TARGET  0                      // 256 int
#define OFF_TOK     1024                   // 64 int
#define OFF_THRI    2048                   // 64 uint
#define OFF_RESK    4096                   // 64 ull (8B aligned)
#define OFF_SCALE   8192                   // 128 float
#define OFF_HBUF    (1u << 20)             // B*H float (1 MB)
#define OFF_XROW    (2u << 20)             // B*H float, x row-major [b][h]
#define OFF_UF      (3u << 20)             // u 3-way bf16 split frags (3 MB)
#define OFF_XF      (6u << 20)             // x bf16 frag layout (512 KB)
#define OFF_DLOGA   (7u << 20)             // V*B float approx logits (8.2 MB)
#define OFF_PART    (16u << 20)            // 16 ks * H * B float = 16.8 MB
#define OFF_LF      (48u << 20)            // lm_head bf16 frag layout (262 MB)

// out layout: accepted[256] | num_accepted[64] | next_draft[192] | next_new[256] | new_past_t[192]
#define OUT_ACC 0
#define OUT_NA  256
#define OUT_NDT 320
#define OUT_NNT 512
#define OUT_NPT 768

#define DELTA 0.75f

__device__ __forceinline__ unsigned short f2bf(float f) {
    unsigned int u = __float_as_uint(f);
    u += 0x7fffu + ((u >> 16) & 1u);       // round-to-nearest-even
    return (unsigned short)(u >> 16);
}
__device__ __forceinline__ float bf2f(unsigned short h) {
    return __uint_as_float(((unsigned int)h) << 16);
}
__device__ __forceinline__ uint4 mku4(const unsigned short* p) {
    return make_uint4((unsigned)p[0] | ((unsigned)p[1] << 16),
                      (unsigned)p[2] | ((unsigned)p[3] << 16),
                      (unsigned)p[4] | ((unsigned)p[5] << 16),
                      (unsigned)p[6] | ((unsigned)p[7] << 16));
}
__device__ __forceinline__ bf16x8_t mkfrag(const unsigned short* p) {
    union { uint4 q; bf16x8_t v; } u;
    u.q = mku4(p);
    return u.v;
}
// monotonic float<->uint key (larger float => larger key); all-zero init < every valid key
__device__ __forceinline__ unsigned fkey(float f) {
    unsigned u = __float_as_uint(f);
    return u ^ ((unsigned)((int)u >> 31) | 0x80000000u);
}
__device__ __forceinline__ float funkey(unsigned k) {
    unsigned u = (k & 0x80000000u) ? (k ^ 0x80000000u) : ~k;
    return __uint_as_float(u);
}

// ------------------------------------------------------------------
// Kernel A: row-wise argmax of logits (256 rows x 32000), first-index tie-break
__global__ void argmax_logits_kernel(const float* __restrict__ logits, int* __restrict__ target) {
    const int r = blockIdx.x;
    const float4* row = (const float4*)(logits + (size_t)r * V);
    float bv = -INFINITY;
    int bi = 0x7fffffff;
    for (int i4 = threadIdx.x; i4 < V / 4; i4 += 256) {
        float4 v = row[i4];
        int base = i4 * 4;
        if (v.x > bv) { bv = v.x; bi = base; }
        if (v.y > bv) { bv = v.y; bi = base + 1; }
        if (v.z > bv) { bv = v.z; bi = base + 2; }
        if (v.w > bv) { bv = v.w; bi = base + 3; }
    }
    __shared__ float sv[256];
    __shared__ int si[256];
    sv[threadIdx.x] = bv; si[threadIdx.x] = bi;
    __syncthreads();
    for (int s = 128; s > 0; s >>= 1) {
        if (threadIdx.x < (unsigned)s) {
            float ov = sv[threadIdx.x + s]; int oi = si[threadIdx.x + s];
            if (ov > sv[threadIdx.x] || (ov == sv[threadIdx.x] && oi < si[threadIdx.x])) {
                sv[threadIdx.x] = ov; si[threadIdx.x] = oi;
            }
        }
        __syncthreads();
    }
    if (threadIdx.x == 0) target[r] = si[0];
}

// ------------------------------------------------------------------
// Kernel B: acceptance logic + outputs + h gather
__global__ void accept_kernel(const int* __restrict__ target, const int* __restrict__ draft,
                              const int* __restrict__ past_t, const int* __restrict__ slot,
                              const float* __restrict__ hs, int* __restrict__ out,
                              int* __restrict__ tok_ws, float* __restrict__ h_buf) {
    const int b = blockIdx.x;
    __shared__ int s_na;
    if (threadIdx.x == 0) {
        const int* trow = target + b * K1;
        const int* drow = draft + b * K;
        int na = 1, prod = 1;
        for (int k = 0; k < K; ++k) { prod *= (drow[k] == trow[k]) ? 1 : 0; na += prod; }
        s_na = na;
        out[OUT_NA + b] = na;
        int srow = slot[b];
        for (int jj = 0; jj < K; ++jj) {
            int idx = na + jj;
            int v = (idx < K) ? past_t[srow * K + idx] : trow[idx - K];
            out[OUT_NPT + b * K + jj] = v;
        }
        int tok0 = trow[na - 1];
        out[OUT_NNT + b * K1 + 0] = tok0;
        tok_ws[b] = tok0;
        for (int i = 0; i < K1; ++i) out[OUT_ACC + b * K1 + i] = trow[i];
    }
    __syncthreads();
    const int na = s_na;
    const float4* src = (const float4*)(hs + ((size_t)b * K1 + (na - 1)) * H);
    float4* dst = (float4*)(h_buf + (size_t)b * H);
    for (int k = threadIdx.x; k < H / 4; k += 256) dst[k] = src[k];
}

// ------------------------------------------------------------------
// Kernel C1: rms scales for both halves; also init thrInt/resKey for this step.
__global__ void rms_scale_kernel(const int* __restrict__ tok_ws, const float* __restrict__ embed,
                                 const float* __restrict__ h_src, float* __restrict__ scales,
                                 unsigned int* __restrict__ thrInt, unsigned long long* __restrict__ resKey) {
    const int b = blockIdx.x, tid = threadIdx.x;
    const int tok = tok_ws[b];
    const float4* e4 = (const float4*)(embed + (size_t)tok * H);
    const float4* h4 = (const float4*)(h_src + (size_t)b * H);
    float se = 0.f, sh = 0.f;
#pragma unroll
    for (int r = 0; r < 4; ++r) {
        float4 e = e4[tid + r * 256];
        float4 h = h4[tid + r * 256];
        se += e.x * e.x + e.y * e.y + e.z * e.z + e.w * e.w;
        sh += h.x * h.x + h.y * h.y + h.z * h.z + h.w * h.w;
    }
    __shared__ float r1[256], r2[256];
    r1[tid] = se; r2[tid] = sh;
    __syncthreads();
    for (int s = 128; s > 0; s >>= 1) {
        if (tid < (unsigned)s) { r1[tid] += r1[tid + s]; r2[tid] += r2[tid + s]; }
        __syncthreads();
    }
    if (tid == 0) {
        scales[b]      = 1.0f / sqrtf(r1[0] * (1.0f / H) + 1e-6f);
        scales[64 + b] = 1.0f / sqrtf(r2[0] * (1.0f / H) + 1e-6f);
        thrInt[b] = 0u;
        resKey[b] = 0ull;
    }
}

// ------------------------------------------------------------------
// Kernel C2: build u 3-way bf16 split directly in MFMA-B-fragment layout.
__global__ __launch_bounds__(256) void build_uf_kernel(const int* __restrict__ tok_ws, const float* __restrict__ embed,
                                                       const float* __restrict__ h_src, const float* __restrict__ scales,
                                                       unsigned short* __restrict__ uf) {
    const int c = blockIdx.x;           // 0..255 (p-chunk of 32)
    const int tid = threadIdx.x;
    const int g = tid >> 6, l = tid & 63;
    const int g4 = l >> 4, li = l & 15;
    const int b = g * 16 + li;
    unsigned short h0[8], h1[8], h2[8];
    const float* src;
    float sc;
    if (c < H / 32) { src = embed + (size_t)tok_ws[b] * H + c * 32; sc = scales[b]; }
    else            { src = h_src + (size_t)b * H + (c - H / 32) * 32; sc = scales[64 + b]; }
#pragma unroll
    for (int i = 0; i < 8; ++i) {
        const float a = src[8 * g4 + i] * sc;
        const unsigned short hh = f2bf(a);
        const float r = a - bf2f(hh);
        const unsigned short mm = f2bf(r);
        const float r2 = r - bf2f(mm);
        h0[i] = hh; h1[i] = mm; h2[i] = f2bf(r2);
    }
    unsigned short* dst = uf + (size_t)(((c * 4 + g) * 3) * 64 + l) * 8;
    *(uint4*)(dst)        = mku4(h0);
    *(uint4*)(dst + 512)  = mku4(h1);
    *(uint4*)(dst + 1024) = mku4(h2);
}

// ------------------------------------------------------------------
// Kernel D: GEMM1 via split-bf16 MFMA (6 passes, near-fp32-exact).
__global__ __launch_bounds__(256) void gemm1_mfma(const float* __restrict__ W,
                                                  const unsigned short* __restrict__ uf,
                                                  float* __restrict__ part) {
    const int tid = threadIdx.x, lane = tid & 63, w = tid >> 6;
    const int bx = blockIdx.x;
    const int ks = blockIdx.y;
    const int vc0 = bx * 8 + w * 2;
    const int g4 = lane >> 4, li = lane & 15;
    const int kbase = ks * 512;

    const bf16x8_t* Bu = (const bf16x8_t*)uf;
    const f32x4_t z = {0.f, 0.f, 0.f, 0.f};
    f32x4_t acc[2][4];
#pragma unroll
    for (int v2 = 0; v2 < 2; ++v2)
#pragma unroll
        for (int bc = 0; bc < 4; ++bc) acc[v2][bc] = z;

    const float* Wb = W + (size_t)(kbase + 8 * g4) * H + vc0 * 16 + li;

    float acur[2][8], anxt[2][8];
#pragma unroll
    for (int v2 = 0; v2 < 2; ++v2)
#pragma unroll
        for (int i = 0; i < 8; ++i) acur[v2][i] = Wb[(size_t)i * H + v2 * 16];

    for (int c = 0; c < 16; ++c) {
        const int cg = ks * 16 + c;
        bf16x8_t br[12];
#pragma unroll
        for (int f = 0; f < 12; ++f) br[f] = Bu[((size_t)cg * 12 + f) * 64 + lane];
        if (c + 1 < 16) {
#pragma unroll
            for (int v2 = 0; v2 < 2; ++v2)
#pragma unroll
                for (int i = 0; i < 8; ++i) anxt[v2][i] = Wb[(size_t)((c + 1) * 32 + i) * H + v2 * 16];
        }
        bf16x8_t A0[2], A1[2], A2[2];
#pragma unroll
        for (int v2 = 0; v2 < 2; ++v2) {
            unsigned short s0[8], s1[8], s2[8];
#pragma unroll
            for (int i = 0; i < 8; ++i) {
                const float a = acur[v2][i];
                const unsigned short hh = f2bf(a);
                const float r = a - bf2f(hh);
                const unsigned short mm = f2bf(r);
                const float r2 = r - bf2f(mm);
                s0[i] = hh; s1[i] = mm; s2[i] = f2bf(r2);
            }
            A0[v2] = mkfrag(s0); A1[v2] = mkfrag(s1); A2[v2] = mkfrag(s2);
        }
#pragma unroll
        for (int v2 = 0; v2 < 2; ++v2) {
#pragma unroll
            for (int bc = 0; bc < 4; ++bc) {
                f32x4_t t = acc[v2][bc];
                t = __builtin_amdgcn_mfma_f32_16x16x32_bf16(A0[v2], br[bc * 3 + 0], t, 0, 0, 0);
                t = __builtin_amdgcn_mfma_f32_16x16x32_bf16(A0[v2], br[bc * 3 + 1], t, 0, 0, 0);
                t = __builtin_amdgcn_mfma_f32_16x16x32_bf16(A1[v2], br[bc * 3 + 0], t, 0, 0, 0);
                t = __builtin_amdgcn_mfma_f32_16x16x32_bf16(A0[v2], br[bc * 3 + 2], t, 0, 0, 0);
                t = __builtin_amdgcn_mfma_f32_16x16x32_bf16(A1[v2], br[bc * 3 + 1], t, 0, 0, 0);
                t = __builtin_amdgcn_mfma_f32_16x16x32_bf16(A2[v2], br[bc * 3 + 0], t, 0, 0, 0);
                acc[v2][bc] = t;
            }
        }
#pragma unroll
        for (int v2 = 0; v2 < 2; ++v2)
#pragma unroll
            for (int i = 0; i < 8; ++i) acur[v2][i] = anxt[v2][i];
    }
#pragma unroll
    for (int v2 = 0; v2 < 2; ++v2) {
        const int obase = (vc0 + v2) * 16 + g4 * 4;
#pragma unroll
        for (int bc = 0; bc < 4; ++bc)
#pragma unroll
            for (int r = 0; r < 4; ++r)
                part[((size_t)ks * H + obase + r) * B + bc * 16 + li] = acc[v2][bc][r];
    }
}

// ------------------------------------------------------------------
// Kernel E: reduce 16 gemm1 partials -> x_row [b][h] AND xf (bf16 B-frag layout).
__global__ __launch_bounds__(256) void reduce1_fused(const float* __restrict__ part, float* __restrict__ x_row,
                                                     unsigned short* __restrict__ xf) {
    const int kc = blockIdx.x;          // 0..127 (h-chunk of 32)
    const int tid = threadIdx.x;
    const int g = tid >> 6, l = tid & 63;
    const int g4 = l >> 4, li = l & 15;
    const int b = g * 16 + li;
    __shared__ float X[32][65];
    float sv[8];
#pragma unroll
    for (int i = 0; i < 8; ++i) {
        const int o = kc * 32 + 8 * g4 + i;
        float s = 0.f;
#pragma unroll
        for (int ks = 0; ks < 16; ++ks) s += part[((size_t)ks * H + o) * B + b];
        sv[i] = s;
        X[8 * g4 + i][b] = s;
    }
    unsigned int u[4];
#pragma unroll
    for (int p = 0; p < 4; ++p)
        u[p] = (unsigned int)f2bf(sv[2 * p]) | ((unsigned int)f2bf(sv[2 * p + 1]) << 16);
    *(uint4*)(xf + (size_t)((kc * 4 + g) * 64 + l) * 8) = make_uint4(u[0], u[1], u[2], u[3]);
    __syncthreads();
    const int b2 = tid >> 2, oq = tid & 3;
    float4 o0, o1;
    o0.x = X[oq * 8 + 0][b2]; o0.y = X[oq * 8 + 1][b2]; o0.z = X[oq * 8 + 2][b2]; o0.w = X[oq * 8 + 3][b2];
    o1.x = X[oq * 8 + 4][b2]; o1.y = X[oq * 8 + 5][b2]; o1.z = X[oq * 8 + 6][b2]; o1.w = X[oq * 8 + 7][b2];
    float* dst = x_row + (size_t)b2 * H + kc * 32 + oq * 8;
    *(float4*)(dst) = o0;
    *(float4*)(dst + 4) = o1;
}

// ------------------------------------------------------------------
// Kernel F0 (step 0 only): GEMM2 reading fp32 lm_head, converting in-register,
// WRITING Lf (bf16 frag layout) for steps 1-2, computing dlogA + atomic per-b max.
__global__ __launch_bounds__(256) void gemm2_mfma_first(const float* __restrict__ L,
                                                        const unsigned short* __restrict__ xf_,
                                                        unsigned short* __restrict__ Lf,
                                                        float* __restrict__ dlogA,
                                                        unsigned int* __restrict__ thrInt) {
    const int tid = threadIdx.x, lane = tid & 63, w = tid >> 6;
    const int vc = blockIdx.x * 4 + w;
    const int g4 = lane >> 4, li = lane & 15;
    const bf16x8_t* Bx = (const bf16x8_t*)xf_;
    // A source: row = vc*16 + li, col = kc*32 + 8*g4 + i  (8 consecutive floats)
    const float* Lbase = L + (size_t)(vc * 16 + li) * H + 8 * g4;

    const f32x4_t z = {0.f, 0.f, 0.f, 0.f};
    f32x4_t acc[4];
#pragma unroll
    for (int g = 0; g < 4; ++g) acc[g] = z;

    float4 arf[4][2];
    bf16x8_t br[4][4];
#pragma unroll
    for (int d = 0; d < 4; ++d) {
        arf[d][0] = *(const float4*)(Lbase + d * 32);
        arf[d][1] = *(const float4*)(Lbase + d * 32 + 4);
#pragma unroll
        for (int g = 0; g < 4; ++g) br[d][g] = Bx[(size_t)(d * 4 + g) * 64 + lane];
    }

    for (int kc = 0; kc < 128; kc += 4) {
#pragma unroll
        for (int d = 0; d < 4; ++d) {
            // convert the 8 fp32 A-elems to bf16 frag; store to Lf
            const float av[8] = {arf[d][0].x, arf[d][0].y, arf[d][0].z, arf[d][0].w,
                                 arf[d][1].x, arf[d][1].y, arf[d][1].z, arf[d][1].w};
            unsigned short hs8[8];
#pragma unroll
            for (int i = 0; i < 8; ++i) hs8[i] = f2bf(av[i]);
            const bf16x8_t afrag = mkfrag(hs8);
            *(uint4*)(Lf + (((size_t)vc * 128 + (kc + d)) * 64 + lane) * 8) = mku4(hs8);
#pragma unroll
            for (int g = 0; g < 4; ++g)
                acc[g] = __builtin_amdgcn_mfma_f32_16x16x32_bf16(afrag, br[d][g], acc[g], 0, 0, 0);
            const int nk = kc + 4 + d;
            if (nk < 128) {
                arf[d][0] = *(const float4*)(Lbase + nk * 32);
                arf[d][1] = *(const float4*)(Lbase + nk * 32 + 4);
#pragma unroll
                for (int g = 0; g < 4; ++g) br[d][g] = Bx[(size_t)(nk * 4 + g) * 64 + lane];
            }
        }
    }

    // per-b max over this block's 64 v + write dlogA
    float m[4];
#pragma unroll
    for (int g = 0; g < 4; ++g) {
        m[g] = fmaxf(fmaxf(acc[g][0], acc[g][1]), fmaxf(acc[g][2], acc[g][3]));
        m[g] = fmaxf(m[g], __shfl_xor(m[g], 16));
        m[g] = fmaxf(m[g], __shfl_xor(m[g], 32));
    }
#pragma unroll
    for (int g = 0; g < 4; ++g) {
        const int vbase = vc * 16 + g4 * 4;
#pragma unroll
        for (int r = 0; r < 4; ++r)
            dlogA[(size_t)(vbase + r) * B + g * 16 + li] = acc[g][r];
    }
    __shared__ float sm[4][4][16];
    if (lane < 16) {
#pragma unroll
        for (int g = 0; g < 4; ++g) sm[w][g][lane] = m[g];
    }
    __syncthreads();
    if (tid < 64) {
        const int gg = tid >> 4, ii = tid & 15;
        const float mm = fmaxf(fmaxf(sm[0][gg][ii], sm[1][gg][ii]), fmaxf(sm[2][gg][ii], sm[3][gg][ii]));
        atomicMax(&thrInt[tid], fkey(mm));
    }
}

// ------------------------------------------------------------------
// Kernel F (steps 1-2): GEMM2 from Lf; dlogA + atomic per-b max.
__global__ __launch_bounds__(256) void gemm2_mfma(const unsigned short* __restrict__ Lf_,
                                                  const unsigned short* __restrict__ xf_,
                                                  float* __restrict__ dlogA,
                                                  unsigned int* __restrict__ thrInt) {
    const int tid = threadIdx.x, lane = tid & 63, w = tid >> 6;
    const int vc = blockIdx.x * 4 + w;
    const bf16x8_t* A = (const bf16x8_t*)Lf_;
    const bf16x8_t* Bx = (const bf16x8_t*)xf_;
    const size_t aBase = (size_t)vc * 128 * 64 + lane;

    const f32x4_t z = {0.f, 0.f, 0.f, 0.f};
    f32x4_t acc[4];
#pragma unroll
    for (int g = 0; g < 4; ++g) acc[g] = z;

    bf16x8_t ar[4];
    bf16x8_t br[4][4];
#pragma unroll
    for (int d = 0; d < 4; ++d) {
        ar[d] = A[aBase + (size_t)d * 64];
#pragma unroll
        for (int g = 0; g < 4; ++g) br[d][g] = Bx[(size_t)(d * 4 + g) * 64 + lane];
    }

    for (int kc = 0; kc < 128; kc += 4) {
#pragma unroll
        for (int d = 0; d < 4; ++d) {
#pragma unroll
            for (int g = 0; g < 4; ++g)
                acc[g] = __builtin_amdgcn_mfma_f32_16x16x32_bf16(ar[d], br[d][g], acc[g], 0, 0, 0);
            const int nk = kc + 4 + d;
            if (nk < 128) {
                ar[d] = A[aBase + (size_t)nk * 64];
#pragma unroll
                for (int g = 0; g < 4; ++g) br[d][g] = Bx[(size_t)(nk * 4 + g) * 64 + lane];
            }
        }
    }

    const int li = lane & 15, g4 = lane >> 4;
    float m[4];
#pragma unroll
    for (int g = 0; g < 4; ++g) {
        m[g] = fmaxf(fmaxf(acc[g][0], acc[g][1]), fmaxf(acc[g][2], acc[g][3]));
        m[g] = fmaxf(m[g], __shfl_xor(m[g], 16));
        m[g] = fmaxf(m[g], __shfl_xor(m[g], 32));
    }
#pragma unroll
    for (int g = 0; g < 4; ++g) {
        const int vbase = vc * 16 + g4 * 4;
#pragma unroll
        for (int r = 0; r < 4; ++r)
            dlogA[(size_t)(vbase + r) * B + g * 16 + li] = acc[g][r];
    }
    __shared__ float sm[4][4][16];
    if (lane < 16) {
#pragma unroll
        for (int g = 0; g < 4; ++g) sm[w][g][lane] = m[g];
    }
    __syncthreads();
    if (tid < 64) {
        const int gg = tid >> 4, ii = tid & 15;
        const float mm = fmaxf(fmaxf(sm[0][gg][ii], sm[1][gg][ii]), fmaxf(sm[2][gg][ii], sm[3][gg][ii]));
        atomicMax(&thrInt[tid], fkey(mm));
    }
}

// ------------------------------------------------------------------
// Kernel CR: fused collect + exact fp32 rescore + deterministic atomic argmax.
// resKey[b] = max over candidates of (fkey(exact_val) << 32 | ~v)  -> order-independent.
__global__ __launch_bounds__(256) void collect_rescore(const float* __restrict__ dlogA,
                                                       const unsigned int* __restrict__ thrInt,
                                                       const float* __restrict__ L,
                                                       const float* __restrict__ x_row,
                                                       unsigned long long* __restrict__ resKey) {
    const int v0 = blockIdx.x * 256;
    __shared__ int s_cnt;
    __shared__ int s_v[256];
    __shared__ int s_b[256];
    if (threadIdx.x == 0) s_cnt = 0;
    __syncthreads();
    for (int i = threadIdx.x; i < 256 * 64; i += 256) {
        const int vl = i >> 6, b = i & 63;
        const float val = dlogA[(size_t)(v0 + vl) * B + b];
        const float thr = funkey(thrInt[b]) - DELTA;
        if (val >= thr) {
            const int s = atomicAdd(&s_cnt, 1);
            if (s < 256) { s_v[s] = v0 + vl; s_b[s] = b; }
        }
    }
    __syncthreads();
    const int n = min(s_cnt, 256);
    const int lane = threadIdx.x & 63, w = threadIdx.x >> 6;
    for (int c = w; c < n; c += 4) {
        const int v = s_v[c], b = s_b[c];
        const float* Lr = L + (size_t)v * H;
        const float* xr = x_row + (size_t)b * H;
        float s = 0.f;
#pragma unroll 8
        for (int t = 0; t < 64; ++t) s = fmaf(Lr[lane + 64 * t], xr[lane + 64 * t], s);
#pragma unroll
        for (int off = 32; off >= 1; off >>= 1) s += __shfl_xor(s, off);
        if (lane == 0) {
            const unsigned long long key = ((unsigned long long)fkey(s) << 32) | (unsigned)(~(unsigned)v);
            atomicMax(&resKey[b], key);
        }
    }
}

// ------------------------------------------------------------------
// Kernel FZ: decode resKey -> token; write outputs for step j.
__global__ void finalize_kernel(const unsigned long long* __restrict__ resKey,
                                int* __restrict__ tok_ws, int* __restrict__ out, int j) {
    const int b = threadIdx.x;   // 64
    const int v = (int)(~(unsigned)(resKey[b] & 0xFFFFFFFFull));
    tok_ws[b] = v;
    out[OUT_NDT + b * K + j] = v;
    out[OUT_NNT + b * K1 + 1 + j] = v;
}

// ------------------------------------------------------------------
extern "C" void kernel_launch(void* const* d_in, const int* in_sizes, int n_in,
                              void* d_out, int out_size, void* d_ws, size_t ws_size,
                              hipStream_t stream) {
    const float* logits  = (const float*)d_in[0];
    const float* hs      = (const float*)d_in[1];
    // d_in[2] past_hidden_pool: provably unused (num_accepted >= 1)
    const float* embed   = (const float*)d_in[3];
    const float* lm_head = (const float*)d_in[4];
    const float* mtp_fc  = (const float*)d_in[5];
    const int* draft     = (const int*)d_in[6];
    const int* past_t    = (const int*)d_in[7];
    const int* slot      = (const int*)d_in[8];
    int* out = (int*)d_out;

    char* ws = (char*)d_ws;
    int* target          = (int*)(ws + OFF_TARGET);
    int* tok_ws          = (int*)(ws + OFF_TOK);
    unsigned int* thrInt = (unsigned int*)(ws + OFF_THRI);
    unsigned long long* resKey = (unsigned long long*)(ws + OFF_RESK);
    float* scales        = (float*)(ws + OFF_SCALE);
    float* h_buf         = (float*)(ws + OFF_HBUF);
    float* x_row         = (float*)(ws + OFF_XROW);
    unsigned short* uf   = (unsigned short*)(ws + OFF_UF);
    unsigned short* xf   = (unsigned short*)(ws + OFF_XF);
    float* dlogA         = (float*)(ws + OFF_DLOGA);
    float* part          = (float*)(ws + OFF_PART);
    unsigned short* Lf   = (unsigned short*)(ws + OFF_LF);

    argmax_logits_kernel<<<B * K1, 256, 0, stream>>>(logits, target);
    accept_kernel<<<B, 256, 0, stream>>>(target, draft, past_t, slot, hs, out, tok_ws, h_buf);

    for (int j = 0; j < K; ++j) {
        const float* h_src = (j == 0) ? h_buf : x_row;
        rms_scale_kernel<<<B, 256, 0, stream>>>(tok_ws, embed, h_src, scales, thrInt, resKey);
        build_uf_kernel<<<2 * H / 32, 256, 0, stream>>>(tok_ws, embed, h_src, scales, uf);
        gemm1_mfma<<<dim3(32, 16), 256, 0, stream>>>(mtp_fc + (size_t)j * 2 * H * H, uf, part);
        reduce1_fused<<<H / 32, 256, 0, stream>>>(part, x_row, xf);
        if (j == 0)
            gemm2_mfma_first<<<V / 64, 256, 0, stream>>>(lm_head, xf, Lf, dlogA, thrInt);
        else
            gemm2_mfma<<<V / 64, 256, 0, stream>>>(Lf, xf, dlogA, thrInt);
        collect_rescore<<<V / 256, 256, 0, stream>>>(dlogA, thrInt, lm_head, x_row, resKey);
        finalize_kernel<<<1, 64, 0, stream>>>(resKey, tok_ws, out, j);
    }
}

// Round 10
// 606.581 us; speedup vs baseline: 8.4372x; 1.0505x over previous
//
#include <hip/hip_runtime.h>
#include <hip/hip_bf16.h>
#include <math.h>

#define B 64
#define K 3
#define H 4096
#define V 32000
#define K1 (K + 1)

typedef short bf16x8_t __attribute__((ext_vector_type(8)));
typedef float f32x4_t __attribute__((ext_vector_type(4)));
typedef long long i64_t;

// ---------------- workspace layout (bytes) ----------------
#define OFF_TARGET  0                      // 256 int
#define OFF_TOK     1024                   // 64 int
#define OFF_THRI    2048                   // 64 uint
#define OFF_RESK    4096                   // 64 ull (8B aligned)
#define OFF_SCALE   8192                   // 128 float
#define OFF_HBUF    (1u << 20)             // B*H float (1 MB)
#define OFF_XROW    (2u << 20)             // B*H float, x row-major [b][h]
#define OFF_UF      (3u << 20)             // u 3-way bf16 split frags (3 MB)
#define OFF_XF      (6u << 20)             // x fp8 frag layout (256 KB)
#define OFF_DLOGA   (7u << 20)             // V*B float approx logits (8.2 MB)
#define OFF_PART    (16u << 20)            // 16 ks * H * B float = 16.8 MB
#define OFF_LF      (48u << 20)            // lm_head fp8 frag layout (131 MB)

// out layout: accepted[256] | num_accepted[64] | next_draft[192] | next_new[256] | new_past_t[192]
#define OUT_ACC 0
#define OUT_NA  256
#define OUT_NDT 320
#define OUT_NNT 512
#define OUT_NPT 768

#define DELTA 1.5f
#define FP8SCALE 16.0f
#define INVACC (1.0f / 256.0f)

__device__ __forceinline__ unsigned short f2bf(float f) {
    unsigned int u = __float_as_uint(f);
    u += 0x7fffu + ((u >> 16) & 1u);       // round-to-nearest-even
    return (unsigned short)(u >> 16);
}
__device__ __forceinline__ float bf2f(unsigned short h) {
    return __uint_as_float(((unsigned int)h) << 16);
}
__device__ __forceinline__ uint4 mku4(const unsigned short* p) {
    return make_uint4((unsigned)p[0] | ((unsigned)p[1] << 16),
                      (unsigned)p[2] | ((unsigned)p[3] << 16),
                      (unsigned)p[4] | ((unsigned)p[5] << 16),
                      (unsigned)p[6] | ((unsigned)p[7] << 16));
}
__device__ __forceinline__ bf16x8_t mkfrag(const unsigned short* p) {
    union { uint4 q; bf16x8_t v; } u;
    u.q = mku4(p);
    return u.v;
}
// monotonic float<->uint key (larger float => larger key); all-zero init < every valid key
__device__ __forceinline__ unsigned fkey(float f) {
    unsigned u = __float_as_uint(f);
    return u ^ ((unsigned)((int)u >> 31) | 0x80000000u);
}
__device__ __forceinline__ float funkey(unsigned k) {
    unsigned u = (k & 0x80000000u) ? (k ^ 0x80000000u) : ~k;
    return __uint_as_float(u);
}
// fp32 -> OCP e4m3fn, round-to-nearest-even, saturate at 448, subnormals handled.
__device__ __forceinline__ unsigned int f2fp8(float f) {
    unsigned u = __float_as_uint(f);
    unsigned sgn = (u >> 24) & 0x80u;
    unsigned au = u & 0x7FFFFFFFu;
    if (au >= 0x43E00000u) return sgn | 0x7Eu;            // clamp to +-448
    if (au < 0x3C800000u) {                               // |f| < 2^-6: subnormal
        float a = __uint_as_float(au);
        int m = (int)rintf(a * 512.0f);                   // steps of 2^-9; m==8 -> min normal
        return sgn | (unsigned)m;
    }
    unsigned r = au + 0x7FFFFu + ((au >> 20) & 1u);       // RNE at 3 mantissa bits
    unsigned e = (r >> 23) - 120u;
    unsigned m = (r >> 20) & 7u;
    return sgn | (e << 3) | m;
}
// pack 8 floats (pre-scaled) into one fp8x8 (i64)
__device__ __forceinline__ unsigned long long pack8fp8(const float* a) {
    unsigned lo = f2fp8(a[0]) | (f2fp8(a[1]) << 8) | (f2fp8(a[2]) << 16) | (f2fp8(a[3]) << 24);
    unsigned hi = f2fp8(a[4]) | (f2fp8(a[5]) << 8) | (f2fp8(a[6]) << 16) | (f2fp8(a[7]) << 24);
    return (unsigned long long)lo | ((unsigned long long)hi << 32);
}

// ------------------------------------------------------------------
// Kernel A: row-wise argmax of logits (256 rows x 32000), first-index tie-break
__global__ void argmax_logits_kernel(const float* __restrict__ logits, int* __restrict__ target) {
    const int r = blockIdx.x;
    const float4* row = (const float4*)(logits + (size_t)r * V);
    float bv = -INFINITY;
    int bi = 0x7fffffff;
    for (int i4 = threadIdx.x; i4 < V / 4; i4 += 256) {
        float4 v = row[i4];
        int base = i4 * 4;
        if (v.x > bv) { bv = v.x; bi = base; }
        if (v.y > bv) { bv = v.y; bi = base + 1; }
        if (v.z > bv) { bv = v.z; bi = base + 2; }
        if (v.w > bv) { bv = v.w; bi = base + 3; }
    }
    __shared__ float sv[256];
    __shared__ int si[256];
    sv[threadIdx.x] = bv; si[threadIdx.x] = bi;
    __syncthreads();
    for (int s = 128; s > 0; s >>= 1) {
        if (threadIdx.x < (unsigned)s) {
            float ov = sv[threadIdx.x + s]; int oi = si[threadIdx.x + s];
            if (ov > sv[threadIdx.x] || (ov == sv[threadIdx.x] && oi < si[threadIdx.x])) {
                sv[threadIdx.x] = ov; si[threadIdx.x] = oi;
            }
        }
        __syncthreads();
    }
    if (threadIdx.x == 0) target[r] = si[0];
}

// ------------------------------------------------------------------
// Kernel B: acceptance logic + outputs + h gather
__global__ void accept_kernel(const int* __restrict__ target, const int* __restrict__ draft,
                              const int* __restrict__ past_t, const int* __restrict__ slot,
                              const float* __restrict__ hs, int* __restrict__ out,
                              int* __restrict__ tok_ws, float* __restrict__ h_buf) {
    const int b = blockIdx.x;
    __shared__ int s_na;
    if (threadIdx.x == 0) {
        const int* trow = target + b * K1;
        const int* drow = draft + b * K;
        int na = 1, prod = 1;
        for (int k = 0; k < K; ++k) { prod *= (drow[k] == trow[k]) ? 1 : 0; na += prod; }
        s_na = na;
        out[OUT_NA + b] = na;
        int srow = slot[b];
        for (int jj = 0; jj < K; ++jj) {
            int idx = na + jj;
            int v = (idx < K) ? past_t[srow * K + idx] : trow[idx - K];
            out[OUT_NPT + b * K + jj] = v;
        }
        int tok0 = trow[na - 1];
        out[OUT_NNT + b * K1 + 0] = tok0;
        tok_ws[b] = tok0;
        for (int i = 0; i < K1; ++i) out[OUT_ACC + b * K1 + i] = trow[i];
    }
    __syncthreads();
    const int na = s_na;
    const float4* src = (const float4*)(hs + ((size_t)b * K1 + (na - 1)) * H);
    float4* dst = (float4*)(h_buf + (size_t)b * H);
    for (int k = threadIdx.x; k < H / 4; k += 256) dst[k] = src[k];
}

// ------------------------------------------------------------------
// Kernel C1: rms scales for both halves; also init thrInt/resKey for this step.
__global__ void rms_scale_kernel(const int* __restrict__ tok_ws, const float* __restrict__ embed,
                                 const float* __restrict__ h_src, float* __restrict__ scales,
                                 unsigned int* __restrict__ thrInt, unsigned long long* __restrict__ resKey) {
    const int b = blockIdx.x, tid = threadIdx.x;
    const int tok = tok_ws[b];
    const float4* e4 = (const float4*)(embed + (size_t)tok * H);
    const float4* h4 = (const float4*)(h_src + (size_t)b * H);
    float se = 0.f, sh = 0.f;
#pragma unroll
    for (int r = 0; r < 4; ++r) {
        float4 e = e4[tid + r * 256];
        float4 h = h4[tid + r * 256];
        se += e.x * e.x + e.y * e.y + e.z * e.z + e.w * e.w;
        sh += h.x * h.x + h.y * h.y + h.z * h.z + h.w * h.w;
    }
    __shared__ float r1[256], r2[256];
    r1[tid] = se; r2[tid] = sh;
    __syncthreads();
    for (int s = 128; s > 0; s >>= 1) {
        if (tid < (unsigned)s) { r1[tid] += r1[tid + s]; r2[tid] += r2[tid + s]; }
        __syncthreads();
    }
    if (tid == 0) {
        scales[b]      = 1.0f / sqrtf(r1[0] * (1.0f / H) + 1e-6f);
        scales[64 + b] = 1.0f / sqrtf(r2[0] * (1.0f / H) + 1e-6f);
        thrInt[b] = 0u;
        resKey[b] = 0ull;
    }
}

// ------------------------------------------------------------------
// Kernel C2: build u 3-way bf16 split directly in MFMA-B-fragment layout.
__global__ __launch_bounds__(256) void build_uf_kernel(const int* __restrict__ tok_ws, const float* __restrict__ embed,
                                                       const float* __restrict__ h_src, const float* __restrict__ scales,
                                                       unsigned short* __restrict__ uf) {
    const int c = blockIdx.x;           // 0..255 (p-chunk of 32)
    const int tid = threadIdx.x;
    const int g = tid >> 6, l = tid & 63;
    const int g4 = l >> 4, li = l & 15;
    const int b = g * 16 + li;
    unsigned short h0[8], h1[8], h2[8];
    const float* src;
    float sc;
    if (c < H / 32) { src = embed + (size_t)tok_ws[b] * H + c * 32; sc = scales[b]; }
    else            { src = h_src + (size_t)b * H + (c - H / 32) * 32; sc = scales[64 + b]; }
#pragma unroll
    for (int i = 0; i < 8; ++i) {
        const float a = src[8 * g4 + i] * sc;
        const unsigned short hh = f2bf(a);
        const float r = a - bf2f(hh);
        const unsigned short mm = f2bf(r);
        const float r2 = r - bf2f(mm);
        h0[i] = hh; h1[i] = mm; h2[i] = f2bf(r2);
    }
    unsigned short* dst = uf + (size_t)(((c * 4 + g) * 3) * 64 + l) * 8;
    *(uint4*)(dst)        = mku4(h0);
    *(uint4*)(dst + 512)  = mku4(h1);
    *(uint4*)(dst + 1024) = mku4(h2);
}

// ------------------------------------------------------------------
// Kernel D: GEMM1 via split-bf16 MFMA (6 passes, near-fp32-exact).
__global__ __launch_bounds__(256) void gemm1_mfma(const float* __restrict__ W,
                                                  const unsigned short* __restrict__ uf,
                                                  float* __restrict__ part) {
    const int tid = threadIdx.x, lane = tid & 63, w = tid >> 6;
    const int bx = blockIdx.x;
    const int ks = blockIdx.y;
    const int vc0 = bx * 8 + w * 2;
    const int g4 = lane >> 4, li = lane & 15;
    const int kbase = ks * 512;

    const bf16x8_t* Bu = (const bf16x8_t*)uf;
    const f32x4_t z = {0.f, 0.f, 0.f, 0.f};
    f32x4_t acc[2][4];
#pragma unroll
    for (int v2 = 0; v2 < 2; ++v2)
#pragma unroll
        for (int bc = 0; bc < 4; ++bc) acc[v2][bc] = z;

    const float* Wb = W + (size_t)(kbase + 8 * g4) * H + vc0 * 16 + li;

    float acur[2][8], anxt[2][8];
#pragma unroll
    for (int v2 = 0; v2 < 2; ++v2)
#pragma unroll
        for (int i = 0; i < 8; ++i) acur[v2][i] = Wb[(size_t)i * H + v2 * 16];

    for (int c = 0; c < 16; ++c) {
        const int cg = ks * 16 + c;
        bf16x8_t br[12];
#pragma unroll
        for (int f = 0; f < 12; ++f) br[f] = Bu[((size_t)cg * 12 + f) * 64 + lane];
        if (c + 1 < 16) {
#pragma unroll
            for (int v2 = 0; v2 < 2; ++v2)
#pragma unroll
                for (int i = 0; i < 8; ++i) anxt[v2][i] = Wb[(size_t)((c + 1) * 32 + i) * H + v2 * 16];
        }
        bf16x8_t A0[2], A1[2], A2[2];
#pragma unroll
        for (int v2 = 0; v2 < 2; ++v2) {
            unsigned short s0[8], s1[8], s2[8];
#pragma unroll
            for (int i = 0; i < 8; ++i) {
                const float a = acur[v2][i];
                const unsigned short hh = f2bf(a);
                const float r = a - bf2f(hh);
                const unsigned short mm = f2bf(r);
                const float r2 = r - bf2f(mm);
                s0[i] = hh; s1[i] = mm; s2[i] = f2bf(r2);
            }
            A0[v2] = mkfrag(s0); A1[v2] = mkfrag(s1); A2[v2] = mkfrag(s2);
        }
#pragma unroll
        for (int v2 = 0; v2 < 2; ++v2) {
#pragma unroll
            for (int bc = 0; bc < 4; ++bc) {
                f32x4_t t = acc[v2][bc];
                t = __builtin_amdgcn_mfma_f32_16x16x32_bf16(A0[v2], br[bc * 3 + 0], t, 0, 0, 0);
                t = __builtin_amdgcn_mfma_f32_16x16x32_bf16(A0[v2], br[bc * 3 + 1], t, 0, 0, 0);
                t = __builtin_amdgcn_mfma_f32_16x16x32_bf16(A1[v2], br[bc * 3 + 0], t, 0, 0, 0);
                t = __builtin_amdgcn_mfma_f32_16x16x32_bf16(A0[v2], br[bc * 3 + 2], t, 0, 0, 0);
                t = __builtin_amdgcn_mfma_f32_16x16x32_bf16(A1[v2], br[bc * 3 + 1], t, 0, 0, 0);
                t = __builtin_amdgcn_mfma_f32_16x16x32_bf16(A2[v2], br[bc * 3 + 0], t, 0, 0, 0);
                acc[v2][bc] = t;
            }
        }
#pragma unroll
        for (int v2 = 0; v2 < 2; ++v2)
#pragma unroll
            for (int i = 0; i < 8; ++i) acur[v2][i] = anxt[v2][i];
    }
#pragma unroll
    for (int v2 = 0; v2 < 2; ++v2) {
        const int obase = (vc0 + v2) * 16 + g4 * 4;
#pragma unroll
        for (int bc = 0; bc < 4; ++bc)
#pragma unroll
            for (int r = 0; r < 4; ++r)
                part[((size_t)ks * H + obase + r) * B + bc * 16 + li] = acc[v2][bc][r];
    }
}

// ------------------------------------------------------------------
// Kernel E: reduce 16 gemm1 partials -> x_row [b][h] AND xf (fp8 B-frag layout, x*16).
__global__ __launch_bounds__(256) void reduce1_fused(const float* __restrict__ part, float* __restrict__ x_row,
                                                     unsigned long long* __restrict__ xf8) {
    const int kc = blockIdx.x;          // 0..127 (h-chunk of 32)
    const int tid = threadIdx.x;
    const int g = tid >> 6, l = tid & 63;
    const int g4 = l >> 4, li = l & 15;
    const int b = g * 16 + li;
    __shared__ float X[32][65];
    float sv[8];
#pragma unroll
    for (int i = 0; i < 8; ++i) {
        const int o = kc * 32 + 8 * g4 + i;
        float s = 0.f;
#pragma unroll
        for (int ks = 0; ks < 16; ++ks) s += part[((size_t)ks * H + o) * B + b];
        sv[i] = s;
        X[8 * g4 + i][b] = s;
    }
    float svs[8];
#pragma unroll
    for (int i = 0; i < 8; ++i) svs[i] = sv[i] * FP8SCALE;
    xf8[(size_t)(kc * 4 + g) * 64 + l] = pack8fp8(svs);
    __syncthreads();
    const int b2 = tid >> 2, oq = tid & 3;
    float4 o0, o1;
    o0.x = X[oq * 8 + 0][b2]; o0.y = X[oq * 8 + 1][b2]; o0.z = X[oq * 8 + 2][b2]; o0.w = X[oq * 8 + 3][b2];
    o1.x = X[oq * 8 + 4][b2]; o1.y = X[oq * 8 + 5][b2]; o1.z = X[oq * 8 + 6][b2]; o1.w = X[oq * 8 + 7][b2];
    float* dst = x_row + (size_t)b2 * H + kc * 32 + oq * 8;
    *(float4*)(dst) = o0;
    *(float4*)(dst + 4) = o1;
}

// ------------------------------------------------------------------
// Kernel F0 (step 0 only): GEMM2 reading fp32 lm_head, converting in-register to fp8 (x16),
// WRITING Lf8 for steps 1-2, computing dlogA + atomic per-b max. acc is (16x)*(16x) = 256x true.
__global__ __launch_bounds__(256) void gemm2_mfma_first(const float* __restrict__ L,
                                                        const unsigned long long* __restrict__ xf8,
                                                        unsigned long long* __restrict__ Lf8,
                                                        float* __restrict__ dlogA,
                                                        unsigned int* __restrict__ thrInt) {
    const int tid = threadIdx.x, lane = tid & 63, w = tid >> 6;
    const int vc = blockIdx.x * 4 + w;
    const int g4 = lane >> 4, li = lane & 15;
    // A source: row = vc*16 + li, col = kc*32 + 8*g4 + i  (8 consecutive floats)
    const float* Lbase = L + (size_t)(vc * 16 + li) * H + 8 * g4;

    const f32x4_t z = {0.f, 0.f, 0.f, 0.f};
    f32x4_t acc[4];
#pragma unroll
    for (int g = 0; g < 4; ++g) acc[g] = z;

    float4 arf[4][2];
    unsigned long long br[4][4];
#pragma unroll
    for (int d = 0; d < 4; ++d) {
        arf[d][0] = *(const float4*)(Lbase + d * 32);
        arf[d][1] = *(const float4*)(Lbase + d * 32 + 4);
#pragma unroll
        for (int g = 0; g < 4; ++g) br[d][g] = xf8[(size_t)(d * 4 + g) * 64 + lane];
    }

    for (int kc = 0; kc < 128; kc += 4) {
#pragma unroll
        for (int d = 0; d < 4; ++d) {
            const float av[8] = {arf[d][0].x * FP8SCALE, arf[d][0].y * FP8SCALE,
                                 arf[d][0].z * FP8SCALE, arf[d][0].w * FP8SCALE,
                                 arf[d][1].x * FP8SCALE, arf[d][1].y * FP8SCALE,
                                 arf[d][1].z * FP8SCALE, arf[d][1].w * FP8SCALE};
            const unsigned long long afrag = pack8fp8(av);
            Lf8[((size_t)vc * 128 + (kc + d)) * 64 + lane] = afrag;
#pragma unroll
            for (int g = 0; g < 4; ++g)
                acc[g] = __builtin_amdgcn_mfma_f32_16x16x32_fp8_fp8((i64_t)afrag, (i64_t)br[d][g], acc[g], 0, 0, 0);
            const int nk = kc + 4 + d;
            if (nk < 128) {
                arf[d][0] = *(const float4*)(Lbase + nk * 32);
                arf[d][1] = *(const float4*)(Lbase + nk * 32 + 4);
#pragma unroll
                for (int g = 0; g < 4; ++g) br[d][g] = xf8[(size_t)(nk * 4 + g) * 64 + lane];
            }
        }
    }

    // rescale to true units, per-b max over this block's 64 v + write dlogA
    float m[4];
#pragma unroll
    for (int g = 0; g < 4; ++g) {
#pragma unroll
        for (int r = 0; r < 4; ++r) acc[g][r] *= INVACC;
        m[g] = fmaxf(fmaxf(acc[g][0], acc[g][1]), fmaxf(acc[g][2], acc[g][3]));
        m[g] = fmaxf(m[g], __shfl_xor(m[g], 16));
        m[g] = fmaxf(m[g], __shfl_xor(m[g], 32));
    }
#pragma unroll
    for (int g = 0; g < 4; ++g) {
        const int vbase = vc * 16 + g4 * 4;
#pragma unroll
        for (int r = 0; r < 4; ++r)
            dlogA[(size_t)(vbase + r) * B + g * 16 + li] = acc[g][r];
    }
    __shared__ float sm[4][4][16];
    if (lane < 16) {
#pragma unroll
        for (int g = 0; g < 4; ++g) sm[w][g][lane] = m[g];
    }
    __syncthreads();
    if (tid < 64) {
        const int gg = tid >> 4, ii = tid & 15;
        const float mm = fmaxf(fmaxf(sm[0][gg][ii], sm[1][gg][ii]), fmaxf(sm[2][gg][ii], sm[3][gg][ii]));
        atomicMax(&thrInt[tid], fkey(mm));
    }
}

// ------------------------------------------------------------------
// Kernel F (steps 1-2): GEMM2 from Lf8 (fp8); dlogA + atomic per-b max.
__global__ __launch_bounds__(256) void gemm2_mfma(const unsigned long long* __restrict__ Lf8,
                                                  const unsigned long long* __restrict__ xf8,
                                                  float* __restrict__ dlogA,
                                                  unsigned int* __restrict__ thrInt) {
    const int tid = threadIdx.x, lane = tid & 63, w = tid >> 6;
    const int vc = blockIdx.x * 4 + w;
    const size_t aBase = (size_t)vc * 128 * 64 + lane;

    const f32x4_t z = {0.f, 0.f, 0.f, 0.f};
    f32x4_t acc[4];
#pragma unroll
    for (int g = 0; g < 4; ++g) acc[g] = z;

    unsigned long long ar[4];
    unsigned long long br[4][4];
#pragma unroll
    for (int d = 0; d < 4; ++d) {
        ar[d] = Lf8[aBase + (size_t)d * 64];
#pragma unroll
        for (int g = 0; g < 4; ++g) br[d][g] = xf8[(size_t)(d * 4 + g) * 64 + lane];
    }

    for (int kc = 0; kc < 128; kc += 4) {
#pragma unroll
        for (int d = 0; d < 4; ++d) {
#pragma unroll
            for (int g = 0; g < 4; ++g)
                acc[g] = __builtin_amdgcn_mfma_f32_16x16x32_fp8_fp8((i64_t)ar[d], (i64_t)br[d][g], acc[g], 0, 0, 0);
            const int nk = kc + 4 + d;
            if (nk < 128) {
                ar[d] = Lf8[aBase + (size_t)nk * 64];
#pragma unroll
                for (int g = 0; g < 4; ++g) br[d][g] = xf8[(size_t)(nk * 4 + g) * 64 + lane];
            }
        }
    }

    const int li = lane & 15, g4 = lane >> 4;
    float m[4];
#pragma unroll
    for (int g = 0; g < 4; ++g) {
#pragma unroll
        for (int r = 0; r < 4; ++r) acc[g][r] *= INVACC;
        m[g] = fmaxf(fmaxf(acc[g][0], acc[g][1]), fmaxf(acc[g][2], acc[g][3]));
        m[g] = fmaxf(m[g], __shfl_xor(m[g], 16));
        m[g] = fmaxf(m[g], __shfl_xor(m[g], 32));
    }
#pragma unroll
    for (int g = 0; g < 4; ++g) {
        const int vbase = vc * 16 + g4 * 4;
#pragma unroll
        for (int r = 0; r < 4; ++r)
            dlogA[(size_t)(vbase + r) * B + g * 16 + li] = acc[g][r];
    }
    __shared__ float sm[4][4][16];
    if (lane < 16) {
#pragma unroll
        for (int g = 0; g < 4; ++g) sm[w][g][lane] = m[g];
    }
    __syncthreads();
    if (tid < 64) {
        const int gg = tid >> 4, ii = tid & 15;
        const float mm = fmaxf(fmaxf(sm[0][gg][ii], sm[1][gg][ii]), fmaxf(sm[2][gg][ii], sm[3][gg][ii]));
        atomicMax(&thrInt[tid], fkey(mm));
    }
}

// ------------------------------------------------------------------
// Kernel CR: fused collect + exact fp32 rescore + deterministic atomic argmax.
// resKey[b] = max over candidates of (fkey(exact_val) << 32 | ~v)  -> order-independent.
__global__ __launch_bounds__(256) void collect_rescore(const float* __restrict__ dlogA,
                                                       const unsigned int* __restrict__ thrInt,
                                                       const float* __restrict__ L,
                                                       const float* __restrict__ x_row,
                                                       unsigned long long* __restrict__ resKey) {
    const int v0 = blockIdx.x * 256;
    __shared__ int s_cnt;
    __shared__ int s_v[512];
    __shared__ int s_b[512];
    if (threadIdx.x == 0) s_cnt = 0;
    __syncthreads();
    for (int i = threadIdx.x; i < 256 * 64; i += 256) {
        const int vl = i >> 6, b = i & 63;
        const float val = dlogA[(size_t)(v0 + vl) * B + b];
        const float thr = funkey(thrInt[b]) - DELTA;
        if (val >= thr) {
            const int s = atomicAdd(&s_cnt, 1);
            if (s < 512) { s_v[s] = v0 + vl; s_b[s] = b; }
        }
    }
    __syncthreads();
    const int n = min(s_cnt, 512);
    const int lane = threadIdx.x & 63, w = threadIdx.x >> 6;
    for (int c = w; c < n; c += 4) {
        const int v = s_v[c], b = s_b[c];
        const float* Lr = L + (size_t)v * H;
        const float* xr = x_row + (size_t)b * H;
        float s = 0.f;
#pragma unroll 8
        for (int t = 0; t < 64; ++t) s = fmaf(Lr[lane + 64 * t], xr[lane + 64 * t], s);
#pragma unroll
        for (int off = 32; off >= 1; off >>= 1) s += __shfl_xor(s, off);
        if (lane == 0) {
            const unsigned long long key = ((unsigned long long)fkey(s) << 32) | (unsigned)(~(unsigned)v);
            atomicMax(&resKey[b], key);
        }
    }
}

// ------------------------------------------------------------------
// Kernel FZ: decode resKey -> token; write outputs for step j.
__global__ void finalize_kernel(const unsigned long long* __restrict__ resKey,
                                int* __restrict__ tok_ws, int* __restrict__ out, int j) {
    const int b = threadIdx.x;   // 64
    const int v = (int)(~(unsigned)(resKey[b] & 0xFFFFFFFFull));
    tok_ws[b] = v;
    out[OUT_NDT + b * K + j] = v;
    out[OUT_NNT + b * K1 + 1 + j] = v;
}

// ------------------------------------------------------------------
extern "C" void kernel_launch(void* const* d_in, const int* in_sizes, int n_in,
                              void* d_out, int out_size, void* d_ws, size_t ws_size,
                              hipStream_t stream) {
    const float* logits  = (const float*)d_in[0];
    const float* hs      = (const float*)d_in[1];
    // d_in[2] past_hidden_pool: provably unused (num_accepted >= 1)
    const float* embed   = (const float*)d_in[3];
    const float* lm_head = (const float*)d_in[4];
    const float* mtp_fc  = (const float*)d_in[5];
    const int* draft     = (const int*)d_in[6];
    const int* past_t    = (const int*)d_in[7];
    const int* slot      = (const int*)d_in[8];
    int* out = (int*)d_out;

    char* ws = (char*)d_ws;
    int* target          = (int*)(ws + OFF_TARGET);
    int* tok_ws          = (int*)(ws + OFF_TOK);
    unsigned int* thrInt = (unsigned int*)(ws + OFF_THRI);
    unsigned long long* resKey = (unsigned long long*)(ws + OFF_RESK);
    float* scales        = (float*)(ws + OFF_SCALE);
    float* h_buf         = (float*)(ws + OFF_HBUF);
    float* x_row         = (float*)(ws + OFF_XROW);
    unsigned short* uf   = (unsigned short*)(ws + OFF_UF);
    unsigned long long* xf8 = (unsigned long long*)(ws + OFF_XF);
    float* dlogA         = (float*)(ws + OFF_DLOGA);
    float* part          = (float*)(ws + OFF_PART);
    unsigned long long* Lf8 = (unsigned long long*)(ws + OFF_LF);

    argmax_logits_kernel<<<B * K1, 256, 0, stream>>>(logits, target);
    accept_kernel<<<B, 256, 0, stream>>>(target, draft, past_t, slot, hs, out, tok_ws, h_buf);

    for (int j = 0; j < K; ++j) {
        const float* h_src = (j == 0) ? h_buf : x_row;
        rms_scale_kernel<<<B, 256, 0, stream>>>(tok_ws, embed, h_src, scales, thrInt, resKey);
        build_uf_kernel<<<2 * H / 32, 256, 0, stream>>>(tok_ws, embed, h_src, scales, uf);
        gemm1_mfma<<<dim3(32, 16), 256, 0, stream>>>(mtp_fc + (size_t)j * 2 * H * H, uf, part);
        reduce1_fused<<<H / 32, 256, 0, stream>>>(part, x_row, xf8);
        if (j == 0)
            gemm2_mfma_first<<<V / 64, 256, 0, stream>>>(lm_head, xf8, Lf8, dlogA, thrInt);
        else
            gemm2_mfma<<<V / 64, 256, 0, stream>>>(Lf8, xf8, dlogA, thrInt);
        collect_rescore<<<V / 256, 256, 0, stream>>>(dlogA, thrInt, lm_head, x_row, resKey);
        finalize_kernel<<<1, 64, 0, stream>>>(resKey, tok_ws, out, j);
    }
}